// Round 1
// baseline (2103.250 us; speedup 1.0000x reference)
//
#include <hip/hip_runtime.h>

#define N_NODES   100000
#define FIELD_DIM 128
#define EMBED_DIM 64
#define N_EDGES   3200000
#define NX        16384   // BATCH * NUM_FIELDS

// ---------------- flag needed nodes + zero their accumulator rows ----------
__global__ void k_flag_zero(const int* __restrict__ x,
                            unsigned char* __restrict__ flag,
                            float4* __restrict__ out_acc4) {
    int g = blockIdx.x * blockDim.x + threadIdx.x;   // [0, NX*16)
    if (g >= NX * 16) return;
    int i = g >> 4, q = g & 15;
    int v = x[i];
    if (q == 0) flag[v] = 1;                 // duplicate writes benign
    out_acc4[(size_t)v * 16 + q] = make_float4(0.f, 0.f, 0.f, 0.f);
}

// ---------------- degree over ALL edges (dst side) -------------------------
__global__ void k_deg(const int* __restrict__ dst, int* __restrict__ cnt, int E) {
    int e = blockIdx.x * blockDim.x + threadIdx.x;
    if (e < E) atomicAdd(&cnt[dst[e]], 1);
}

__global__ void k_dinv(const int* __restrict__ cnt, float* __restrict__ dinv, int n) {
    int v = blockIdx.x * blockDim.x + threadIdx.x;
    if (v < n) dinv[v] = rsqrtf((float)cnt[v] + 1.0f);   // +1 self loop
}

// ---------------- h = F (100000x128) @ W (128x64) --------------------------
__global__ __launch_bounds__(256) void k_gemm(const float* __restrict__ F,
                                              const float* __restrict__ W,
                                              float* __restrict__ h, int n) {
    __shared__ float fs[64][132];   // stride 132 floats: bank step 4 -> 2-way max
    __shared__ float wt[64][132];   // wt[c][k] = W[k][c]
    int tid = threadIdx.x;

    for (int i = tid; i < FIELD_DIM * EMBED_DIM; i += 256) {
        int k = i >> 6, c = i & 63;
        wt[c][k] = W[i];
    }
    int row0 = blockIdx.x * 64;
    for (int i = tid; i < 64 * 32; i += 256) {       // float4 units
        int r = i >> 5, kq = i & 31;
        int row = row0 + r;
        float4 v = (row < n) ? ((const float4*)F)[(size_t)row * 32 + kq]
                             : make_float4(0.f, 0.f, 0.f, 0.f);
        *(float4*)&fs[r][kq * 4] = v;
    }
    __syncthreads();

    int cg = tid & 15;   // cols cg*4 .. cg*4+3
    int rg = tid >> 4;   // rows rg*4 .. rg*4+3
    float acc[4][4];
#pragma unroll
    for (int i = 0; i < 4; ++i)
#pragma unroll
        for (int j = 0; j < 4; ++j) acc[i][j] = 0.f;

    for (int k = 0; k < 128; k += 4) {
        float4 a[4], b[4];
#pragma unroll
        for (int i = 0; i < 4; ++i) a[i] = *(const float4*)&fs[rg * 4 + i][k];
#pragma unroll
        for (int j = 0; j < 4; ++j) b[j] = *(const float4*)&wt[cg * 4 + j][k];
#pragma unroll
        for (int i = 0; i < 4; ++i)
#pragma unroll
            for (int j = 0; j < 4; ++j)
                acc[i][j] += a[i].x * b[j].x + a[i].y * b[j].y +
                             a[i].z * b[j].z + a[i].w * b[j].w;
    }
#pragma unroll
    for (int i = 0; i < 4; ++i) {
        int row = row0 + rg * 4 + i;
        if (row < n) {
            float4 r = make_float4(acc[i][0], acc[i][1], acc[i][2], acc[i][3]);
            *(float4*)&h[(size_t)row * 64 + cg * 4] = r;
        }
    }
}

// ---------------- scatter messages for flagged destinations ----------------
__global__ __launch_bounds__(256) void k_msg(const int* __restrict__ src,
                                             const int* __restrict__ dst,
                                             const float* __restrict__ h,
                                             const float* __restrict__ dinv,
                                             const unsigned char* __restrict__ flag,
                                             float* __restrict__ out_acc, int E) {
    int e = blockIdx.x * blockDim.x + threadIdx.x;
    if (e >= E) return;
    int d = dst[e];
    if (!flag[d]) return;                      // ~85% of lanes exit here
    int s = src[e];
    float nrm = dinv[s] * dinv[d];
    const float4* hs = (const float4*)(h + (size_t)s * 64);
    float* od = out_acc + (size_t)d * 64;
#pragma unroll
    for (int q = 0; q < 16; ++q) {
        float4 v = hs[q];
        atomicAdd(od + 4 * q + 0, v.x * nrm);
        atomicAdd(od + 4 * q + 1, v.y * nrm);
        atomicAdd(od + 4 * q + 2, v.z * nrm);
        atomicAdd(od + 4 * q + 3, v.w * nrm);
    }
}

// ---------------- final gather: acc + self-loop + bias ---------------------
__global__ void k_gather(const int* __restrict__ x,
                         const float* __restrict__ out_acc,
                         const float* __restrict__ h,
                         const float* __restrict__ dinv,
                         const float* __restrict__ bias,
                         float* __restrict__ out) {
    int g = blockIdx.x * blockDim.x + threadIdx.x;   // [0, NX*16)
    if (g >= NX * 16) return;
    int i = g >> 4, q = g & 15;
    int v = x[i];
    float dv = dinv[v];
    float c2 = dv * dv;                              // self-loop norm
    float4 a  = ((const float4*)(out_acc + (size_t)v * 64))[q];
    float4 hv = ((const float4*)(h + (size_t)v * 64))[q];
    float4 bb = ((const float4*)bias)[q];
    float4 r = make_float4(a.x + hv.x * c2 + bb.x,
                           a.y + hv.y * c2 + bb.y,
                           a.z + hv.z * c2 + bb.z,
                           a.w + hv.w * c2 + bb.w);
    ((float4*)out)[(size_t)i * 16 + q] = r;
}

extern "C" void kernel_launch(void* const* d_in, const int* in_sizes, int n_in,
                              void* d_out, int out_size, void* d_ws, size_t ws_size,
                              hipStream_t stream) {
    const float* features = (const float*)d_in[0];
    const int*   edge     = (const int*)d_in[1];
    const float* W        = (const float*)d_in[2];
    const float* bias     = (const float*)d_in[3];
    const int*   x        = (const int*)d_in[4];
    float* out = (float*)d_out;

    char* ws = (char*)d_ws;
    float*         h       = (float*)(ws);                    // 25,600,000 B
    float*         out_acc = (float*)(ws + 25600000);         // 25,600,000 B
    int*           cnt     = (int*)  (ws + 51200000);         //    400,000 B
    float*         dinv    = (float*)(ws + 51600000);         //    400,000 B
    unsigned char* flag    = (unsigned char*)(ws + 52000000); //    100,000 B

    const int* esrc = edge;
    const int* edst = edge + N_EDGES;

    hipMemsetAsync(cnt, 0, N_NODES * sizeof(int), stream);
    hipMemsetAsync(flag, 0, N_NODES, stream);

    k_flag_zero<<<(NX * 16 + 255) / 256, 256, 0, stream>>>(x, flag, (float4*)out_acc);
    k_deg <<<(N_EDGES + 255) / 256, 256, 0, stream>>>(edst, cnt, N_EDGES);
    k_dinv<<<(N_NODES + 255) / 256, 256, 0, stream>>>(cnt, dinv, N_NODES);
    k_gemm<<<(N_NODES + 63) / 64, 256, 0, stream>>>(features, W, h, N_NODES);
    k_msg <<<(N_EDGES + 255) / 256, 256, 0, stream>>>(esrc, edst, h, dinv, flag,
                                                      out_acc, N_EDGES);
    k_gather<<<(NX * 16 + 255) / 256, 256, 0, stream>>>(x, out_acc, h, dinv, bias, out);
}

// Round 2
// 303.985 us; speedup vs baseline: 6.9189x; 6.9189x over previous
//
#include <hip/hip_runtime.h>

#define N_NODES   100000
#define FIELD_DIM 128
#define EMBED_DIM 64
#define N_EDGES   3200000
#define NX        16384   // BATCH * NUM_FIELDS

// ---------------- flag needed nodes ----------------------------------------
__global__ void k_flag(const int* __restrict__ x, unsigned char* __restrict__ flag) {
    int i = blockIdx.x * blockDim.x + threadIdx.x;
    if (i < NX) flag[x[i]] = 1;               // duplicate writes benign
}

// ---------------- degree over ALL edges (dst side) -------------------------
__global__ void k_deg(const int* __restrict__ dst, int* __restrict__ cnt, int E) {
    int e = blockIdx.x * blockDim.x + threadIdx.x;
    if (e < E) atomicAdd(&cnt[dst[e]], 1);
}

__global__ void k_dinv(const int* __restrict__ cnt, float* __restrict__ dinv, int n) {
    int v = blockIdx.x * blockDim.x + threadIdx.x;
    if (v < n) dinv[v] = rsqrtf((float)cnt[v] + 1.0f);   // +1 self loop
}

// ---------------- compact flagged nodes, claim elist segments --------------
// counters[0] = nflag, counters[1] = ecur
__global__ void k_compact(const unsigned char* __restrict__ flag,
                          const int* __restrict__ cnt,
                          int* __restrict__ nlist, int* __restrict__ inv,
                          int* __restrict__ off, int* __restrict__ counters, int n) {
    int v = blockIdx.x * blockDim.x + threadIdx.x;
    if (v >= n || !flag[v]) return;
    int i = atomicAdd(&counters[0], 1);
    nlist[i] = v;
    inv[v] = i;
    off[v] = atomicAdd(&counters[1], cnt[v]);
}

// ---------------- h = F (100000x128) @ W (128x64) --------------------------
__global__ __launch_bounds__(256) void k_gemm(const float* __restrict__ F,
                                              const float* __restrict__ W,
                                              float* __restrict__ h, int n) {
    __shared__ float fs[64][132];
    __shared__ float wt[64][132];   // wt[c][k] = W[k][c]
    int tid = threadIdx.x;

    for (int i = tid; i < FIELD_DIM * EMBED_DIM; i += 256) {
        int k = i >> 6, c = i & 63;
        wt[c][k] = W[i];
    }
    int row0 = blockIdx.x * 64;
    for (int i = tid; i < 64 * 32; i += 256) {       // float4 units
        int r = i >> 5, kq = i & 31;
        int row = row0 + r;
        float4 v = (row < n) ? ((const float4*)F)[(size_t)row * 32 + kq]
                             : make_float4(0.f, 0.f, 0.f, 0.f);
        *(float4*)&fs[r][kq * 4] = v;
    }
    __syncthreads();

    int cg = tid & 15;
    int rg = tid >> 4;
    float acc[4][4];
#pragma unroll
    for (int i = 0; i < 4; ++i)
#pragma unroll
        for (int j = 0; j < 4; ++j) acc[i][j] = 0.f;

    for (int k = 0; k < 128; k += 4) {
        float4 a[4], b[4];
#pragma unroll
        for (int i = 0; i < 4; ++i) a[i] = *(const float4*)&fs[rg * 4 + i][k];
#pragma unroll
        for (int j = 0; j < 4; ++j) b[j] = *(const float4*)&wt[cg * 4 + j][k];
#pragma unroll
        for (int i = 0; i < 4; ++i)
#pragma unroll
            for (int j = 0; j < 4; ++j)
                acc[i][j] += a[i].x * b[j].x + a[i].y * b[j].y +
                             a[i].z * b[j].z + a[i].w * b[j].w;
    }
#pragma unroll
    for (int i = 0; i < 4; ++i) {
        int row = row0 + rg * 4 + i;
        if (row < n) {
            float4 r = make_float4(acc[i][0], acc[i][1], acc[i][2], acc[i][3]);
            *(float4*)&h[(size_t)row * 64 + cg * 4] = r;
        }
    }
}

// ---------------- fill in-edge lists for flagged destinations --------------
__global__ __launch_bounds__(256) void k_fill(const int* __restrict__ src,
                                              const int* __restrict__ dst,
                                              const unsigned char* __restrict__ flag,
                                              const int* __restrict__ off,
                                              int* __restrict__ cur,
                                              int* __restrict__ elist, int E) {
    int e = blockIdx.x * blockDim.x + threadIdx.x;
    if (e >= E) return;
    int d = dst[e];
    if (!flag[d]) return;                      // ~85% of lanes exit here
    int p = atomicAdd(&cur[d], 1);
    elist[off[d] + p] = src[e];
}

// ---------------- pull: one wave per flagged node --------------------------
__global__ __launch_bounds__(256) void k_pull(const int* __restrict__ nlist,
                                              const int* __restrict__ counters,
                                              const int* __restrict__ cnt,
                                              const int* __restrict__ off,
                                              const int* __restrict__ elist,
                                              const float* __restrict__ h,
                                              const float* __restrict__ dinv,
                                              const float* __restrict__ bias,
                                              float* __restrict__ accc) {
    int t = blockIdx.x * blockDim.x + threadIdx.x;
    int wid = t >> 6;              // wave id = compact node index
    int lane = t & 63;
    if (wid >= counters[0]) return;
    int v = nlist[wid];
    float dvd = dinv[v];
    int deg = cnt[v];
    int base = off[v];
    // self-loop + bias
    float acc = h[(size_t)v * 64 + lane] * (dvd * dvd) + bias[lane];
    int j = 0;
    for (; j + 1 < deg; j += 2) {
        int s0 = elist[base + j];
        int s1 = elist[base + j + 1];
        float n0 = dinv[s0] * dvd;
        float n1 = dinv[s1] * dvd;
        float v0 = h[(size_t)s0 * 64 + lane];
        float v1 = h[(size_t)s1 * 64 + lane];
        acc += v0 * n0;
        acc += v1 * n1;
    }
    if (j < deg) {
        int s0 = elist[base + j];
        acc += h[(size_t)s0 * 64 + lane] * (dinv[s0] * dvd);
    }
    accc[(size_t)wid * 64 + lane] = acc;
}

// ---------------- final gather: out[b] = accc[inv[x[b]]] -------------------
__global__ void k_gather(const int* __restrict__ x,
                         const int* __restrict__ inv,
                         const float* __restrict__ accc,
                         float* __restrict__ out) {
    int g = blockIdx.x * blockDim.x + threadIdx.x;   // [0, NX*64)
    if (g >= NX * 64) return;
    int v = x[g >> 6];
    out[g] = accc[(size_t)inv[v] * 64 + (g & 63)];
}

extern "C" void kernel_launch(void* const* d_in, const int* in_sizes, int n_in,
                              void* d_out, int out_size, void* d_ws, size_t ws_size,
                              hipStream_t stream) {
    const float* features = (const float*)d_in[0];
    const int*   edge     = (const int*)d_in[1];
    const float* W        = (const float*)d_in[2];
    const float* bias     = (const float*)d_in[3];
    const int*   x        = (const int*)d_in[4];
    float* out = (float*)d_out;

    char* ws = (char*)d_ws;
    float*         h        = (float*)(ws);                     // 25,600,000 B
    float*         accc     = (float*)(ws + 25600000);          //  4,194,304 B
    int*           cnt      = (int*)  (ws + 29794304);          //    400,000 B
    float*         dinv     = (float*)(ws + 30194304);          //    400,000 B
    int*           off      = (int*)  (ws + 30594304);          //    400,000 B
    int*           cur      = (int*)  (ws + 30994304);          //    400,000 B
    int*           inv      = (int*)  (ws + 31394304);          //    400,000 B
    int*           nlist    = (int*)  (ws + 31794304);          //     65,536 B
    int*           counters = (int*)  (ws + 31859840);          //          8 B
    unsigned char* flag     = (unsigned char*)(ws + 31859848);  //    100,000 B
    int*           elist    = (int*)  (ws + 31960064);          // 12,800,000 B

    const int* esrc = edge;
    const int* edst = edge + N_EDGES;

    hipMemsetAsync(cnt, 0, N_NODES * sizeof(int), stream);
    hipMemsetAsync(cur, 0, N_NODES * sizeof(int), stream);
    hipMemsetAsync(counters, 0, 8, stream);
    hipMemsetAsync(flag, 0, N_NODES, stream);

    k_flag   <<<(NX + 255) / 256, 256, 0, stream>>>(x, flag);
    k_deg    <<<(N_EDGES + 255) / 256, 256, 0, stream>>>(edst, cnt, N_EDGES);
    k_dinv   <<<(N_NODES + 255) / 256, 256, 0, stream>>>(cnt, dinv, N_NODES);
    k_compact<<<(N_NODES + 255) / 256, 256, 0, stream>>>(flag, cnt, nlist, inv, off,
                                                         counters, N_NODES);
    k_gemm   <<<(N_NODES + 63) / 64, 256, 0, stream>>>(features, W, h, N_NODES);
    k_fill   <<<(N_EDGES + 255) / 256, 256, 0, stream>>>(esrc, edst, flag, off, cur,
                                                         elist, N_EDGES);
    k_pull   <<<(NX * 64 + 255) / 256, 256, 0, stream>>>(nlist, counters, cnt, off,
                                                         elist, h, dinv, bias, accc);
    k_gather <<<(NX * 64 + 255) / 256, 256, 0, stream>>>(x, inv, accc, out);
}

// Round 3
// 185.303 us; speedup vs baseline: 11.3503x; 1.6405x over previous
//
#include <hip/hip_runtime.h>

#define N_NODES   100000
#define FIELD_DIM 128
#define EMBED_DIM 64
#define N_EDGES   3200000
#define NX        16384   // BATCH * NUM_FIELDS

#define QN        12500   // nodes per histogram range (8 ranges)
#define NSLICE    64      // edge slices
#define SLICE_E   (N_EDGES / NSLICE)   // 50000

// ---------------- flag needed nodes ----------------------------------------
__global__ void k_flag(const int* __restrict__ x, unsigned char* __restrict__ flag) {
    int i = blockIdx.x * blockDim.x + threadIdx.x;
    if (i < NX) flag[x[i]] = 1;               // duplicate writes benign
}

// ---------------- degree histogram: LDS-privatized, 8 ranges x 64 slices ---
__global__ __launch_bounds__(256) void k_hist(const int* __restrict__ dst,
                                              unsigned short* __restrict__ partial) {
    __shared__ int hist[QN];                  // 50,000 B
    int tid = threadIdx.x;
    int q = blockIdx.x & 7, s = blockIdx.x >> 3;
    for (int i = tid; i < QN; i += 256) hist[i] = 0;
    __syncthreads();
    int lo = q * QN;
    const int4* dp = (const int4*)(dst + s * SLICE_E);
    for (int i = tid; i < SLICE_E / 4; i += 256) {
        int4 d = dp[i];
        int a;
        a = d.x - lo; if ((unsigned)a < QN) atomicAdd(&hist[a], 1);
        a = d.y - lo; if ((unsigned)a < QN) atomicAdd(&hist[a], 1);
        a = d.z - lo; if ((unsigned)a < QN) atomicAdd(&hist[a], 1);
        a = d.w - lo; if ((unsigned)a < QN) atomicAdd(&hist[a], 1);
    }
    __syncthreads();
    // pack u16 pairs, coalesced u32 stores; per-slice count <= 50000 fits u16
    unsigned int* po = (unsigned int*)(partial + (size_t)blockIdx.x * QN);
    for (int i = tid; i < QN / 2; i += 256) {
        unsigned int v = ((unsigned int)hist[2 * i] & 0xFFFFu) |
                         ((unsigned int)hist[2 * i + 1] << 16);
        po[i] = v;
    }
}

// ---------------- reduce partials + dinv + wave-aggregated compaction ------
__global__ __launch_bounds__(256) void k_reduce(const unsigned short* __restrict__ partial,
                                                const unsigned char* __restrict__ flag,
                                                int* __restrict__ cnt,
                                                float* __restrict__ dinv,
                                                int* __restrict__ nlist,
                                                int* __restrict__ inv,
                                                int* __restrict__ off,
                                                int* __restrict__ counters) {
    int v = blockIdx.x * blockDim.x + threadIdx.x;
    int lane = threadIdx.x & 63;
    bool inb = (v < N_NODES);
    int c = 0;
    if (inb) {
        int q = v / QN, loc = v - q * QN;
        const unsigned short* p = partial + (size_t)q * QN + loc;
#pragma unroll 8
        for (int s = 0; s < NSLICE; ++s) c += p[(size_t)s * 8 * QN];
        cnt[v] = c;
        dinv[v] = rsqrtf((float)c + 1.0f);    // +1 self loop
    }
    bool fl = inb && flag[v];
    unsigned long long mask = __ballot(fl);
    int myi = __popcll(mask & ((1ull << lane) - 1));
    int tot = __popcll(mask);
    int cc = fl ? c : 0;
    int incl = cc;
#pragma unroll
    for (int o = 1; o < 64; o <<= 1) {
        int t = __shfl_up(incl, o);
        if (lane >= o) incl += t;
    }
    int wsum = __shfl(incl, 63);
    int b0 = 0, b1 = 0;
    if (lane == 0) {
        if (tot)  b0 = atomicAdd(&counters[0], tot);
        if (wsum) b1 = atomicAdd(&counters[1], wsum);
    }
    b0 = __shfl(b0, 0);
    b1 = __shfl(b1, 0);
    if (fl) {
        int i = b0 + myi;
        nlist[i] = v;
        inv[v] = i;
        off[v] = b1 + (incl - cc);
    }
}

// ---------------- h = F (100000x128) @ W (128x64) --------------------------
__global__ __launch_bounds__(256) void k_gemm(const float* __restrict__ F,
                                              const float* __restrict__ W,
                                              float* __restrict__ h, int n) {
    __shared__ float fs[64][132];
    __shared__ float wt[64][132];   // wt[c][k] = W[k][c]
    int tid = threadIdx.x;

    for (int i = tid; i < FIELD_DIM * EMBED_DIM; i += 256) {
        int k = i >> 6, c = i & 63;
        wt[c][k] = W[i];
    }
    int row0 = blockIdx.x * 64;
    for (int i = tid; i < 64 * 32; i += 256) {       // float4 units
        int r = i >> 5, kq = i & 31;
        int row = row0 + r;
        float4 v = (row < n) ? ((const float4*)F)[(size_t)row * 32 + kq]
                             : make_float4(0.f, 0.f, 0.f, 0.f);
        *(float4*)&fs[r][kq * 4] = v;
    }
    __syncthreads();

    int cg = tid & 15;
    int rg = tid >> 4;
    float acc[4][4];
#pragma unroll
    for (int i = 0; i < 4; ++i)
#pragma unroll
        for (int j = 0; j < 4; ++j) acc[i][j] = 0.f;

    for (int k = 0; k < 128; k += 4) {
        float4 a[4], b[4];
#pragma unroll
        for (int i = 0; i < 4; ++i) a[i] = *(const float4*)&fs[rg * 4 + i][k];
#pragma unroll
        for (int j = 0; j < 4; ++j) b[j] = *(const float4*)&wt[cg * 4 + j][k];
#pragma unroll
        for (int i = 0; i < 4; ++i)
#pragma unroll
            for (int j = 0; j < 4; ++j)
                acc[i][j] += a[i].x * b[j].x + a[i].y * b[j].y +
                             a[i].z * b[j].z + a[i].w * b[j].w;
    }
#pragma unroll
    for (int i = 0; i < 4; ++i) {
        int row = row0 + rg * 4 + i;
        if (row < n) {
            float4 r = make_float4(acc[i][0], acc[i][1], acc[i][2], acc[i][3]);
            *(float4*)&h[(size_t)row * 64 + cg * 4] = r;
        }
    }
}

// ---------------- fill in-edge lists for flagged destinations --------------
__global__ __launch_bounds__(256) void k_fill(const int* __restrict__ src,
                                              const int* __restrict__ dst,
                                              const unsigned char* __restrict__ flag,
                                              const int* __restrict__ off,
                                              int* __restrict__ cur,
                                              int* __restrict__ elist) {
    int i = blockIdx.x * blockDim.x + threadIdx.x;
    if (i >= N_EDGES / 4) return;
    int4 d4 = ((const int4*)dst)[i];
    int4 s4 = ((const int4*)src)[i];
#define FILL1(dd, ss) if (flag[dd]) { int p = atomicAdd(&cur[dd], 1); elist[off[dd] + p] = ss; }
    FILL1(d4.x, s4.x)
    FILL1(d4.y, s4.y)
    FILL1(d4.z, s4.z)
    FILL1(d4.w, s4.w)
#undef FILL1
}

// ---------------- pull: one wave per flagged node --------------------------
__global__ __launch_bounds__(256) void k_pull(const int* __restrict__ nlist,
                                              const int* __restrict__ counters,
                                              const int* __restrict__ cnt,
                                              const int* __restrict__ off,
                                              const int* __restrict__ elist,
                                              const float* __restrict__ h,
                                              const float* __restrict__ dinv,
                                              const float* __restrict__ bias,
                                              float* __restrict__ accc) {
    int t = blockIdx.x * blockDim.x + threadIdx.x;
    int wid = t >> 6;              // wave id = compact node index
    int lane = t & 63;
    if (wid >= counters[0]) return;
    int v = nlist[wid];
    float dvd = dinv[v];
    int deg = cnt[v];
    int base = off[v];
    // self-loop + bias
    float acc = h[(size_t)v * 64 + lane] * (dvd * dvd) + bias[lane];
    int j = 0;
    for (; j + 3 < deg; j += 4) {
        int s0 = elist[base + j];
        int s1 = elist[base + j + 1];
        int s2 = elist[base + j + 2];
        int s3 = elist[base + j + 3];
        float n0 = dinv[s0] * dvd;
        float n1 = dinv[s1] * dvd;
        float n2 = dinv[s2] * dvd;
        float n3 = dinv[s3] * dvd;
        acc += h[(size_t)s0 * 64 + lane] * n0;
        acc += h[(size_t)s1 * 64 + lane] * n1;
        acc += h[(size_t)s2 * 64 + lane] * n2;
        acc += h[(size_t)s3 * 64 + lane] * n3;
    }
    for (; j < deg; ++j) {
        int s0 = elist[base + j];
        acc += h[(size_t)s0 * 64 + lane] * (dinv[s0] * dvd);
    }
    accc[(size_t)wid * 64 + lane] = acc;
}

// ---------------- final gather: out[b] = accc[inv[x[b]]] -------------------
__global__ void k_gather(const int* __restrict__ x,
                         const int* __restrict__ inv,
                         const float* __restrict__ accc,
                         float* __restrict__ out) {
    int g = blockIdx.x * blockDim.x + threadIdx.x;   // [0, NX*64)
    if (g >= NX * 64) return;
    int v = x[g >> 6];
    out[g] = accc[(size_t)inv[v] * 64 + (g & 63)];
}

extern "C" void kernel_launch(void* const* d_in, const int* in_sizes, int n_in,
                              void* d_out, int out_size, void* d_ws, size_t ws_size,
                              hipStream_t stream) {
    const float* features = (const float*)d_in[0];
    const int*   edge     = (const int*)d_in[1];
    const float* W        = (const float*)d_in[2];
    const float* bias     = (const float*)d_in[3];
    const int*   x        = (const int*)d_in[4];
    float* out = (float*)d_out;

    char* ws = (char*)d_ws;
    float*          h        = (float*)(ws);                     // 25,600,000 B
    unsigned short* partial  = (unsigned short*)(ws + 25600000); // 12,800,000 B
    int*            elist    = (int*)(ws + 25600000);            // overlay: live after partial
    float*          accc     = (float*)(ws + 38400000);          //  4,194,304 B
    int*            cnt      = (int*)  (ws + 42594304);          //    400,000 B
    float*          dinv     = (float*)(ws + 42994304);          //    400,000 B
    int*            off      = (int*)  (ws + 43394304);          //    400,000 B
    int*            inv      = (int*)  (ws + 43794304);          //    400,000 B
    int*            nlist    = (int*)  (ws + 44194304);          //     65,536 B
    int*            cur      = (int*)  (ws + 44259840);          //    400,000 B
    int*            counters = (int*)  (ws + 44659840);          //         32 B
    unsigned char*  flag     = (unsigned char*)(ws + 44659872);  //    100,000 B

    const int* esrc = edge;
    const int* edst = edge + N_EDGES;

    // one memset covers cur + counters + flag (contiguous)
    hipMemsetAsync(cur, 0, 500032, stream);

    k_flag  <<<(NX + 255) / 256, 256, 0, stream>>>(x, flag);
    k_hist  <<<8 * NSLICE, 256, 0, stream>>>(edst, partial);
    k_reduce<<<(N_NODES + 255) / 256, 256, 0, stream>>>(partial, flag, cnt, dinv,
                                                        nlist, inv, off, counters);
    k_gemm  <<<(N_NODES + 63) / 64, 256, 0, stream>>>(features, W, h, N_NODES);
    k_fill  <<<(N_EDGES / 4 + 255) / 256, 256, 0, stream>>>(esrc, edst, flag, off,
                                                            cur, elist);
    k_pull  <<<(NX * 64 + 255) / 256, 256, 0, stream>>>(nlist, counters, cnt, off,
                                                        elist, h, dinv, bias, accc);
    k_gather<<<(NX * 64 + 255) / 256, 256, 0, stream>>>(x, inv, accc, out);
}

// Round 4
// 170.167 us; speedup vs baseline: 12.3599x; 1.0889x over previous
//
#include <hip/hip_runtime.h>

#define N_NODES   100000
#define FIELD_DIM 128
#define EMBED_DIM 64
#define N_EDGES   3200000
#define NX        16384   // BATCH * NUM_FIELDS

#define QN        12500   // nodes per histogram range (8 ranges)
#define NSLICE    64      // edge slices
#define SLICE_E   (N_EDGES / NSLICE)   // 50000

__device__ __forceinline__ unsigned short f2bf(float x) {
    unsigned u = __float_as_uint(x);
    u += 0x7FFF + ((u >> 16) & 1);          // round-to-nearest-even
    return (unsigned short)(u >> 16);
}
__device__ __forceinline__ float bf2f(unsigned short b) {
    return __uint_as_float(((unsigned)b) << 16);
}

// ---------------- flag needed nodes ----------------------------------------
__global__ void k_flag(const int* __restrict__ x, unsigned char* __restrict__ flag) {
    int i = blockIdx.x * blockDim.x + threadIdx.x;
    if (i < NX) flag[x[i]] = 1;               // duplicate writes benign
}

// ---------------- degree histogram: LDS-privatized, 8 ranges x 64 slices ---
__global__ __launch_bounds__(256) void k_hist(const int* __restrict__ dst,
                                              unsigned short* __restrict__ partial) {
    __shared__ int hist[QN];                  // 50,000 B
    int tid = threadIdx.x;
    int q = blockIdx.x & 7, s = blockIdx.x >> 3;
    for (int i = tid; i < QN; i += 256) hist[i] = 0;
    __syncthreads();
    int lo = q * QN;
    const int4* dp = (const int4*)(dst + s * SLICE_E);
    for (int i = tid; i < SLICE_E / 4; i += 256) {
        int4 d = dp[i];
        int a;
        a = d.x - lo; if ((unsigned)a < QN) atomicAdd(&hist[a], 1);
        a = d.y - lo; if ((unsigned)a < QN) atomicAdd(&hist[a], 1);
        a = d.z - lo; if ((unsigned)a < QN) atomicAdd(&hist[a], 1);
        a = d.w - lo; if ((unsigned)a < QN) atomicAdd(&hist[a], 1);
    }
    __syncthreads();
    unsigned int* po = (unsigned int*)(partial + (size_t)blockIdx.x * QN);
    for (int i = tid; i < QN / 2; i += 256) {
        unsigned int v = ((unsigned int)hist[2 * i] & 0xFFFFu) |
                         ((unsigned int)hist[2 * i + 1] << 16);
        po[i] = v;
    }
}

// ---------------- reduce partials + dinv + wave-aggregated compaction ------
__global__ __launch_bounds__(256) void k_reduce(const unsigned short* __restrict__ partial,
                                                const unsigned char* __restrict__ flag,
                                                int* __restrict__ cnt,
                                                float* __restrict__ dinv,
                                                int* __restrict__ nlist,
                                                int* __restrict__ inv,
                                                int* __restrict__ off,
                                                int* __restrict__ counters) {
    int v = blockIdx.x * blockDim.x + threadIdx.x;
    int lane = threadIdx.x & 63;
    bool inb = (v < N_NODES);
    int c = 0;
    if (inb) {
        int q = v / QN, loc = v - q * QN;
        const unsigned short* p = partial + (size_t)q * QN + loc;
#pragma unroll 8
        for (int s = 0; s < NSLICE; ++s) c += p[(size_t)s * 8 * QN];
        cnt[v] = c;
        dinv[v] = rsqrtf((float)c + 1.0f);    // +1 self loop
    }
    bool fl = inb && flag[v];
    unsigned long long mask = __ballot(fl);
    int myi = __popcll(mask & ((1ull << lane) - 1));
    int tot = __popcll(mask);
    int cc = fl ? c : 0;
    int incl = cc;
#pragma unroll
    for (int o = 1; o < 64; o <<= 1) {
        int t = __shfl_up(incl, o);
        if (lane >= o) incl += t;
    }
    int wsum = __shfl(incl, 63);
    int b0 = 0, b1 = 0;
    if (lane == 0) {
        if (tot)  b0 = atomicAdd(&counters[0], tot);
        if (wsum) b1 = atomicAdd(&counters[1], wsum);
    }
    b0 = __shfl(b0, 0);
    b1 = __shfl(b1, 0);
    if (fl) {
        int i = b0 + myi;
        nlist[i] = v;
        inv[v] = i;
        off[v] = b1 + (incl - cc);
    }
}

// ---------------- h(bf16) = F (100000x128) @ W (128x64) --------------------
// 256 thr/block, 128 rows/block. W staged once in LDS [k][c] (linear, 32KB).
// Thread (cg=tid&15, rg=tid>>4) computes rows {rg+16i} x cols {cg*4..cg*4+3}.
__global__ __launch_bounds__(256) void k_gemm(const float* __restrict__ F,
                                              const float* __restrict__ W,
                                              unsigned short* __restrict__ h, int n) {
    __shared__ float ws[FIELD_DIM * EMBED_DIM];   // 32 KB, ws[k*64+c]
    int tid = threadIdx.x;
    {
        const float4* W4 = (const float4*)W;
        float4* ws4 = (float4*)ws;
#pragma unroll
        for (int q = 0; q < 8; ++q) ws4[tid + 256 * q] = W4[tid + 256 * q];
    }
    __syncthreads();

    int cg = tid & 15;
    int rg = tid >> 4;
    int row0 = blockIdx.x * 128;
    const float4* F4 = (const float4*)F;          // 32 float4 per row
    bool full = (row0 + 128 <= n);

    float acc[8][4];
#pragma unroll
    for (int i = 0; i < 8; ++i)
#pragma unroll
        for (int j = 0; j < 4; ++j) acc[i][j] = 0.f;

    for (int ks = 0; ks < 32; ++ks) {             // k = 4*ks
        float4 a[8];
        if (full) {
#pragma unroll
            for (int i = 0; i < 8; ++i)
                a[i] = F4[(size_t)(row0 + rg + 16 * i) * 32 + ks];
        } else {
#pragma unroll
            for (int i = 0; i < 8; ++i) {
                int row = row0 + rg + 16 * i;
                a[i] = (row < n) ? F4[(size_t)row * 32 + ks]
                                 : make_float4(0.f, 0.f, 0.f, 0.f);
            }
        }
        const float* wrow = ws + 4 * ks * 64 + cg * 4;
        float4 w0 = *(const float4*)(wrow);
        float4 w1 = *(const float4*)(wrow + 64);
        float4 w2 = *(const float4*)(wrow + 128);
        float4 w3 = *(const float4*)(wrow + 192);
        float wvf[4][4] = {{w0.x, w0.y, w0.z, w0.w},
                           {w1.x, w1.y, w1.z, w1.w},
                           {w2.x, w2.y, w2.z, w2.w},
                           {w3.x, w3.y, w3.z, w3.w}};
#pragma unroll
        for (int i = 0; i < 8; ++i) {
            float4 av = a[i];
#pragma unroll
            for (int j = 0; j < 4; ++j)
                acc[i][j] += av.x * wvf[0][j] + av.y * wvf[1][j] +
                             av.z * wvf[2][j] + av.w * wvf[3][j];
        }
    }
#pragma unroll
    for (int i = 0; i < 8; ++i) {
        int row = row0 + rg + 16 * i;
        if (row < n) {
            ushort4 r = make_ushort4(f2bf(acc[i][0]), f2bf(acc[i][1]),
                                     f2bf(acc[i][2]), f2bf(acc[i][3]));
            *(ushort4*)(h + (size_t)row * 64 + cg * 4) = r;
        }
    }
}

// ---------------- fill in-edge lists for flagged destinations --------------
__global__ __launch_bounds__(256) void k_fill(const int* __restrict__ src,
                                              const int* __restrict__ dst,
                                              const unsigned char* __restrict__ flag,
                                              const int* __restrict__ off,
                                              int* __restrict__ cur,
                                              int* __restrict__ elist) {
    int i = blockIdx.x * blockDim.x + threadIdx.x;
    if (i >= N_EDGES / 4) return;
    int4 d4 = ((const int4*)dst)[i];
    int4 s4 = ((const int4*)src)[i];
#define FILL1(dd, ss) if (flag[dd]) { int p = atomicAdd(&cur[dd], 1); elist[off[dd] + p] = ss; }
    FILL1(d4.x, s4.x)
    FILL1(d4.y, s4.y)
    FILL1(d4.z, s4.z)
    FILL1(d4.w, s4.w)
#undef FILL1
}

// ---------------- pull: one wave per flagged node --------------------------
__global__ __launch_bounds__(256) void k_pull(const int* __restrict__ nlist,
                                              const int* __restrict__ counters,
                                              const int* __restrict__ cnt,
                                              const int* __restrict__ off,
                                              const int* __restrict__ elist,
                                              const unsigned short* __restrict__ h,
                                              const float* __restrict__ dinv,
                                              const float* __restrict__ bias,
                                              float* __restrict__ accc) {
    int t = blockIdx.x * blockDim.x + threadIdx.x;
    int wid = t >> 6;              // wave id = compact node index
    int lane = t & 63;
    if (wid >= counters[0]) return;
    int v = nlist[wid];
    float dvd = dinv[v];
    int deg = cnt[v];
    int base = off[v];
    // self-loop + bias
    float acc = bf2f(h[(size_t)v * 64 + lane]) * (dvd * dvd) + bias[lane];
    int j = 0;
    for (; j + 3 < deg; j += 4) {
        int s0 = elist[base + j];
        int s1 = elist[base + j + 1];
        int s2 = elist[base + j + 2];
        int s3 = elist[base + j + 3];
        float n0 = dinv[s0] * dvd;
        float n1 = dinv[s1] * dvd;
        float n2 = dinv[s2] * dvd;
        float n3 = dinv[s3] * dvd;
        acc += bf2f(h[(size_t)s0 * 64 + lane]) * n0;
        acc += bf2f(h[(size_t)s1 * 64 + lane]) * n1;
        acc += bf2f(h[(size_t)s2 * 64 + lane]) * n2;
        acc += bf2f(h[(size_t)s3 * 64 + lane]) * n3;
    }
    for (; j < deg; ++j) {
        int s0 = elist[base + j];
        acc += bf2f(h[(size_t)s0 * 64 + lane]) * (dinv[s0] * dvd);
    }
    accc[(size_t)wid * 64 + lane] = acc;
}

// ---------------- final gather: out[b] = accc[inv[x[b]]] -------------------
__global__ void k_gather(const int* __restrict__ x,
                         const int* __restrict__ inv,
                         const float* __restrict__ accc,
                         float* __restrict__ out) {
    int g = blockIdx.x * blockDim.x + threadIdx.x;   // [0, NX*64)
    if (g >= NX * 64) return;
    int v = x[g >> 6];
    out[g] = accc[(size_t)inv[v] * 64 + (g & 63)];
}

extern "C" void kernel_launch(void* const* d_in, const int* in_sizes, int n_in,
                              void* d_out, int out_size, void* d_ws, size_t ws_size,
                              hipStream_t stream) {
    const float* features = (const float*)d_in[0];
    const int*   edge     = (const int*)d_in[1];
    const float* W        = (const float*)d_in[2];
    const float* bias     = (const float*)d_in[3];
    const int*   x        = (const int*)d_in[4];
    float* out = (float*)d_out;

    char* ws = (char*)d_ws;
    unsigned short* h16      = (unsigned short*)(ws);            // 12,800,000 B
    unsigned short* partial  = (unsigned short*)(ws + 12800000); // 12,800,000 B
    int*            elist    = (int*)(ws + 12800000);            // overlay: live after k_reduce
    float*          accc     = (float*)(ws + 25600000);          //  4,194,304 B
    int*            cnt      = (int*)  (ws + 29794304);          //    400,000 B
    float*          dinv     = (float*)(ws + 30194304);          //    400,000 B
    int*            off      = (int*)  (ws + 30594304);          //    400,000 B
    int*            inv      = (int*)  (ws + 30994304);          //    400,000 B
    int*            nlist    = (int*)  (ws + 31394304);          //     65,536 B
    int*            cur      = (int*)  (ws + 31459840);          //    400,000 B
    int*            counters = (int*)  (ws + 31859840);          //         32 B
    unsigned char*  flag     = (unsigned char*)(ws + 31859872);  //    100,000 B

    const int* esrc = edge;
    const int* edst = edge + N_EDGES;

    // one memset covers cur + counters + flag (contiguous)
    hipMemsetAsync(cur, 0, 500032, stream);

    k_flag  <<<(NX + 255) / 256, 256, 0, stream>>>(x, flag);
    k_hist  <<<8 * NSLICE, 256, 0, stream>>>(edst, partial);
    k_reduce<<<(N_NODES + 255) / 256, 256, 0, stream>>>(partial, flag, cnt, dinv,
                                                        nlist, inv, off, counters);
    k_gemm  <<<(N_NODES + 127) / 128, 256, 0, stream>>>(features, W, h16, N_NODES);
    k_fill  <<<(N_EDGES / 4 + 255) / 256, 256, 0, stream>>>(esrc, edst, flag, off,
                                                            cur, elist);
    k_pull  <<<(NX * 64 + 255) / 256, 256, 0, stream>>>(nlist, counters, cnt, off,
                                                        elist, h16, dinv, bias, accc);
    k_gather<<<(NX * 64 + 255) / 256, 256, 0, stream>>>(x, inv, accc, out);
}

// Round 6
// 161.971 us; speedup vs baseline: 12.9854x; 1.0506x over previous
//
#include <hip/hip_runtime.h>

#define N_NODES   100000
#define FIELD_DIM 128
#define EMBED_DIM 64
#define N_EDGES   3200000
#define NX        16384   // BATCH * NUM_FIELDS

#define QN        12500   // nodes per histogram range (8 ranges)
#define NSLICE    64      // edge slices
#define SLICE_E   (N_EDGES / NSLICE)   // 50000

typedef short  bf16x8 __attribute__((ext_vector_type(8)));
typedef float  f32x4  __attribute__((ext_vector_type(4)));

__device__ __forceinline__ unsigned short f2bf(float x) {
    unsigned u = __float_as_uint(x);
    u += 0x7FFF + ((u >> 16) & 1);          // round-to-nearest-even
    return (unsigned short)(u >> 16);
}
__device__ __forceinline__ float bf2f(unsigned short b) {
    return __uint_as_float(((unsigned)b) << 16);
}
__device__ __forceinline__ unsigned pk2(float lo, float hi) {
    return (unsigned)f2bf(lo) | ((unsigned)f2bf(hi) << 16);
}

// ---------------- init: flag needed nodes (blocks 0..63) + W transpose -----
// Wt: bf16 Wt[c][k] (64 x 128), LINEAR layout, byte addr c*256 + k*2.
__global__ void k_init(const int* __restrict__ x, unsigned char* __restrict__ flag,
                       const float* __restrict__ W, unsigned short* __restrict__ Wt) {
    int b = blockIdx.x;
    if (b < 64) {
        int i = b * 256 + threadIdx.x;      // NX = 64*256 exactly
        flag[x[i]] = 1;                     // duplicate writes benign
    } else {
        for (int i = threadIdx.x; i < FIELD_DIM * EMBED_DIM; i += 256) {
            int k = i >> 6, c = i & 63;
            Wt[c * FIELD_DIM + k] = f2bf(W[i]);
        }
    }
}

// ---------------- degree histogram: LDS-privatized, 8 ranges x 64 slices ---
__global__ __launch_bounds__(256) void k_hist(const int* __restrict__ dst,
                                              unsigned short* __restrict__ partial) {
    __shared__ int hist[QN];                  // 50,000 B
    int tid = threadIdx.x;
    int q = blockIdx.x & 7, s = blockIdx.x >> 3;
    for (int i = tid; i < QN; i += 256) hist[i] = 0;
    __syncthreads();
    int lo = q * QN;
    const int4* dp = (const int4*)(dst + s * SLICE_E);
    for (int i = tid; i < SLICE_E / 4; i += 256) {
        int4 d = dp[i];
        int a;
        a = d.x - lo; if ((unsigned)a < QN) atomicAdd(&hist[a], 1);
        a = d.y - lo; if ((unsigned)a < QN) atomicAdd(&hist[a], 1);
        a = d.z - lo; if ((unsigned)a < QN) atomicAdd(&hist[a], 1);
        a = d.w - lo; if ((unsigned)a < QN) atomicAdd(&hist[a], 1);
    }
    __syncthreads();
    unsigned int* po = (unsigned int*)(partial + (size_t)blockIdx.x * QN);
    for (int i = tid; i < QN / 2; i += 256) {
        unsigned int v = ((unsigned int)hist[2 * i] & 0xFFFFu) |
                         ((unsigned int)hist[2 * i + 1] << 16);
        po[i] = v;
    }
}

// ---------------- reduce partials + dinv + wave-aggregated compaction ------
__global__ __launch_bounds__(256) void k_reduce(const unsigned short* __restrict__ partial,
                                                const unsigned char* __restrict__ flag,
                                                int* __restrict__ cnt,
                                                float* __restrict__ dinv,
                                                int* __restrict__ nlist,
                                                int* __restrict__ inv,
                                                int* __restrict__ off,
                                                int* __restrict__ counters) {
    int v = blockIdx.x * blockDim.x + threadIdx.x;
    int lane = threadIdx.x & 63;
    bool inb = (v < N_NODES);
    int c = 0;
    if (inb) {
        int q = v / QN, loc = v - q * QN;
        const unsigned short* p = partial + (size_t)q * QN + loc;
#pragma unroll 8
        for (int s = 0; s < NSLICE; ++s) c += p[(size_t)s * 8 * QN];
        cnt[v] = c;
        dinv[v] = rsqrtf((float)c + 1.0f);    // +1 self loop
    }
    bool fl = inb && flag[v];
    unsigned long long mask = __ballot(fl);
    int myi = __popcll(mask & ((1ull << lane) - 1));
    int tot = __popcll(mask);
    int cc = fl ? c : 0;
    int incl = cc;
#pragma unroll
    for (int o = 1; o < 64; o <<= 1) {
        int t = __shfl_up(incl, o);
        if (lane >= o) incl += t;
    }
    int wsum = __shfl(incl, 63);
    int b0 = 0, b1 = 0;
    if (lane == 0) {
        if (tot)  b0 = atomicAdd(&counters[0], tot);
        if (wsum) b1 = atomicAdd(&counters[1], wsum);
    }
    b0 = __shfl(b0, 0);
    b1 = __shfl(b1, 0);
    if (fl) {
        int i = b0 + myi;
        nlist[i] = v;
        inv[v] = i;
        off[v] = b1 + (incl - cc);
    }
}

// ---------------- h(bf16) = F @ W via MFMA 16x16x32, B in registers --------
// 256 thr = 4 waves/block, 64 rows/block. Wave w: rows [b*64+w*16, +16) x all 64 cols.
// A: direct global float4 loads (8 contiguous k per lane), packed to bf16.
// B: 16 statically-indexed bf16x8 fragments per lane, loaded once from Wt.
//    Fragment (cb,ks): lane needs Wt[cb*16 + l15][ks*32 + kg*8 .. +7].
__global__ __launch_bounds__(256) void k_gemm(const float* __restrict__ F,
                                              const unsigned short* __restrict__ Wt,
                                              unsigned short* __restrict__ h, int n) {
    int tid = threadIdx.x;
    int wave = tid >> 6, lane = tid & 63;
    int l15 = lane & 15, kg = lane >> 4;

    const char* wb = (const char*)Wt;
    bf16x8 bfrag[4][4];
#pragma unroll
    for (int cb = 0; cb < 4; ++cb)
#pragma unroll
        for (int ks = 0; ks < 4; ++ks)
            bfrag[cb][ks] = *(const bf16x8*)(wb + (cb * 16 + l15) * 256 + ks * 64 + kg * 16);

    int row = blockIdx.x * 64 + wave * 16 + l15;
    int rowc = min(row, n - 1);                    // clamp; stores are guarded
    const float4* F4 = (const float4*)(F + (size_t)rowc * FIELD_DIM + kg * 8);

    f32x4 acc[4];
#pragma unroll
    for (int cb = 0; cb < 4; ++cb) acc[cb] = (f32x4){0.f, 0.f, 0.f, 0.f};

#pragma unroll
    for (int ks = 0; ks < 4; ++ks) {               // K = 32 per step
        float4 fa = F4[ks * 8];                    // k = 32ks + 8kg + 0..3
        float4 fb = F4[ks * 8 + 1];                // k = 32ks + 8kg + 4..7
        union { bf16x8 v; unsigned u[4]; } af;
        af.u[0] = pk2(fa.x, fa.y);
        af.u[1] = pk2(fa.z, fa.w);
        af.u[2] = pk2(fb.x, fb.y);
        af.u[3] = pk2(fb.z, fb.w);
#pragma unroll
        for (int cb = 0; cb < 4; ++cb)
            acc[cb] = __builtin_amdgcn_mfma_f32_16x16x32_bf16(af.v, bfrag[cb][ks],
                                                              acc[cb], 0, 0, 0);
    }
    // D: col = cb*16 + l15, row = blockbase + wave*16 + kg*4 + reg
    int rbase = blockIdx.x * 64 + wave * 16 + kg * 4;
#pragma unroll
    for (int r = 0; r < 4; ++r) {
        int orow = rbase + r;
        if (orow < n) {
            unsigned short* hp = h + (size_t)orow * 64 + l15;
#pragma unroll
            for (int cb = 0; cb < 4; ++cb) hp[cb * 16] = f2bf(acc[cb][r]);
        }
    }
}

// ---------------- fill in-edge lists for flagged destinations --------------
__global__ __launch_bounds__(256) void k_fill(const int* __restrict__ src,
                                              const int* __restrict__ dst,
                                              const unsigned char* __restrict__ flag,
                                              const int* __restrict__ off,
                                              int* __restrict__ cur,
                                              int* __restrict__ elist) {
    int i = blockIdx.x * blockDim.x + threadIdx.x;
    if (i >= N_EDGES / 4) return;
    int4 d4 = ((const int4*)dst)[i];
    int4 s4 = ((const int4*)src)[i];
#define FILL1(dd, ss) if (flag[dd]) { int p = atomicAdd(&cur[dd], 1); elist[off[dd] + p] = ss; }
    FILL1(d4.x, s4.x)
    FILL1(d4.y, s4.y)
    FILL1(d4.z, s4.z)
    FILL1(d4.w, s4.w)
#undef FILL1
}

// ---------------- pull: one wave per flagged node --------------------------
__global__ __launch_bounds__(256) void k_pull(const int* __restrict__ nlist,
                                              const int* __restrict__ counters,
                                              const int* __restrict__ cnt,
                                              const int* __restrict__ off,
                                              const int* __restrict__ elist,
                                              const unsigned short* __restrict__ h,
                                              const float* __restrict__ dinv,
                                              const float* __restrict__ bias,
                                              float* __restrict__ accc) {
    int t = blockIdx.x * blockDim.x + threadIdx.x;
    int wid = t >> 6;              // wave id = compact node index
    int lane = t & 63;
    if (wid >= counters[0]) return;
    int v = nlist[wid];
    float dvd = dinv[v];
    int deg = cnt[v];
    int base = off[v];
    float acc = bf2f(h[(size_t)v * 64 + lane]) * (dvd * dvd) + bias[lane];
    int j = 0;
    for (; j + 3 < deg; j += 4) {
        int s0 = elist[base + j];
        int s1 = elist[base + j + 1];
        int s2 = elist[base + j + 2];
        int s3 = elist[base + j + 3];
        float n0 = dinv[s0] * dvd;
        float n1 = dinv[s1] * dvd;
        float n2 = dinv[s2] * dvd;
        float n3 = dinv[s3] * dvd;
        acc += bf2f(h[(size_t)s0 * 64 + lane]) * n0;
        acc += bf2f(h[(size_t)s1 * 64 + lane]) * n1;
        acc += bf2f(h[(size_t)s2 * 64 + lane]) * n2;
        acc += bf2f(h[(size_t)s3 * 64 + lane]) * n3;
    }
    for (; j < deg; ++j) {
        int s0 = elist[base + j];
        acc += bf2f(h[(size_t)s0 * 64 + lane]) * (dinv[s0] * dvd);
    }
    accc[(size_t)wid * 64 + lane] = acc;
}

// ---------------- final gather: out[b] = accc[inv[x[b]]] -------------------
__global__ void k_gather(const int* __restrict__ x,
                         const int* __restrict__ inv,
                         const float* __restrict__ accc,
                         float* __restrict__ out) {
    int g = blockIdx.x * blockDim.x + threadIdx.x;   // [0, NX*64)
    if (g >= NX * 64) return;
    int v = x[g >> 6];
    out[g] = accc[(size_t)inv[v] * 64 + (g & 63)];
}

extern "C" void kernel_launch(void* const* d_in, const int* in_sizes, int n_in,
                              void* d_out, int out_size, void* d_ws, size_t ws_size,
                              hipStream_t stream) {
    const float* features = (const float*)d_in[0];
    const int*   edge     = (const int*)d_in[1];
    const float* W        = (const float*)d_in[2];
    const float* bias     = (const float*)d_in[3];
    const int*   x        = (const int*)d_in[4];
    float* out = (float*)d_out;

    char* ws = (char*)d_ws;
    unsigned short* h16      = (unsigned short*)(ws);            // 12,800,000 B
    unsigned short* partial  = (unsigned short*)(ws + 12800000); // 12,800,000 B
    int*            elist    = (int*)(ws + 12800000);            // overlay: live after k_reduce
    float*          accc     = (float*)(ws + 25600000);          //  4,194,304 B
    int*            cnt      = (int*)  (ws + 29794304);          //    400,000 B
    float*          dinv     = (float*)(ws + 30194304);          //    400,000 B
    int*            off      = (int*)  (ws + 30594304);          //    400,000 B
    int*            inv      = (int*)  (ws + 30994304);          //    400,000 B
    int*            nlist    = (int*)  (ws + 31394304);          //     65,536 B
    int*            cur      = (int*)  (ws + 31459840);          //    400,000 B
    int*            counters = (int*)  (ws + 31859840);          //         32 B
    unsigned char*  flag     = (unsigned char*)(ws + 31859872);  //    100,000 B
    unsigned short* Wt       = (unsigned short*)(ws + 31959872); //     16,384 B

    const int* esrc = edge;
    const int* edst = edge + N_EDGES;

    // one memset covers cur + counters + flag (contiguous)
    hipMemsetAsync(cur, 0, 500032, stream);

    k_init  <<<65, 256, 0, stream>>>(x, flag, W, Wt);
    k_hist  <<<8 * NSLICE, 256, 0, stream>>>(edst, partial);
    k_reduce<<<(N_NODES + 255) / 256, 256, 0, stream>>>(partial, flag, cnt, dinv,
                                                        nlist, inv, off, counters);
    k_gemm  <<<(N_NODES + 63) / 64, 256, 0, stream>>>(features, Wt, h16, N_NODES);
    k_fill  <<<(N_EDGES / 4 + 255) / 256, 256, 0, stream>>>(esrc, edst, flag, off,
                                                            cur, elist);
    k_pull  <<<(NX * 64 + 255) / 256, 256, 0, stream>>>(nlist, counters, cnt, off,
                                                        elist, h16, dinv, bias, accc);
    k_gather<<<(NX * 64 + 255) / 256, 256, 0, stream>>>(x, inv, accc, out);
}

// Round 7
// 161.267 us; speedup vs baseline: 13.0420x; 1.0044x over previous
//
#include <hip/hip_runtime.h>

#define N_NODES   100000
#define FIELD_DIM 128
#define EMBED_DIM 64
#define N_EDGES   3200000
#define NX        16384   // BATCH * NUM_FIELDS

#define QN        12500   // nodes per histogram range (8 ranges)
#define NSLICE    64      // edge slices
#define SLICE_E   (N_EDGES / NSLICE)   // 50000

typedef short  bf16x8 __attribute__((ext_vector_type(8)));
typedef float  f32x4  __attribute__((ext_vector_type(4)));

__device__ __forceinline__ unsigned short f2bf(float x) {
    unsigned u = __float_as_uint(x);
    u += 0x7FFF + ((u >> 16) & 1);          // round-to-nearest-even
    return (unsigned short)(u >> 16);
}
__device__ __forceinline__ float bf2f(unsigned short b) {
    return __uint_as_float(((unsigned)b) << 16);
}
__device__ __forceinline__ unsigned pk2(float lo, float hi) {
    return (unsigned)f2bf(lo) | ((unsigned)f2bf(hi) << 16);
}

// ---------------- init: flag needed nodes (blocks 0..63) + W transpose -----
// Wt: bf16 Wt[c][k] (64 x 128), LINEAR layout, byte addr c*256 + k*2.
__global__ void k_init(const int* __restrict__ x, unsigned char* __restrict__ flag,
                       const float* __restrict__ W, unsigned short* __restrict__ Wt) {
    int b = blockIdx.x;
    if (b < 64) {
        int i = b * 256 + threadIdx.x;      // NX = 64*256 exactly
        flag[x[i]] = 1;                     // duplicate writes benign
    } else {
        for (int i = threadIdx.x; i < FIELD_DIM * EMBED_DIM; i += 256) {
            int k = i >> 6, c = i & 63;
            Wt[c * FIELD_DIM + k] = f2bf(W[i]);
        }
    }
}

// ---------------- degree histogram: LDS-privatized, 8 ranges x 64 slices ---
__global__ __launch_bounds__(256) void k_hist(const int* __restrict__ dst,
                                              unsigned short* __restrict__ partial) {
    __shared__ int hist[QN];                  // 50,000 B
    int tid = threadIdx.x;
    int q = blockIdx.x & 7, s = blockIdx.x >> 3;
    for (int i = tid; i < QN; i += 256) hist[i] = 0;
    __syncthreads();
    int lo = q * QN;
    const int4* dp = (const int4*)(dst + s * SLICE_E);
    for (int i = tid; i < SLICE_E / 4; i += 256) {
        int4 d = dp[i];
        int a;
        a = d.x - lo; if ((unsigned)a < QN) atomicAdd(&hist[a], 1);
        a = d.y - lo; if ((unsigned)a < QN) atomicAdd(&hist[a], 1);
        a = d.z - lo; if ((unsigned)a < QN) atomicAdd(&hist[a], 1);
        a = d.w - lo; if ((unsigned)a < QN) atomicAdd(&hist[a], 1);
    }
    __syncthreads();
    unsigned int* po = (unsigned int*)(partial + (size_t)blockIdx.x * QN);
    for (int i = tid; i < QN / 2; i += 256) {
        unsigned int v = ((unsigned int)hist[2 * i] & 0xFFFFu) |
                         ((unsigned int)hist[2 * i + 1] << 16);
        po[i] = v;
    }
}

// ---------------- reduce partials + dinv + wave-aggregated compaction ------
// 1024 thr/block: 4 slice-groups x 256 nodes. Slice loads forced into a
// register array first (back-to-back issue, no serial load->wait->add chain).
__global__ __launch_bounds__(1024) void k_reduce(const unsigned short* __restrict__ partial,
                                                 const unsigned char* __restrict__ flag,
                                                 int* __restrict__ cnt,
                                                 float* __restrict__ dinv,
                                                 int* __restrict__ nlist,
                                                 int* __restrict__ inv,
                                                 int* __restrict__ off,
                                                 int* __restrict__ counters) {
    __shared__ int ssum[1024];
    int tid = threadIdx.x;
    int nloc = tid & 255, sg = tid >> 8;      // 4 slice groups of 16 slices
    int v = blockIdx.x * 256 + nloc;
    bool inb = (v < N_NODES);
    int vc = inb ? v : (N_NODES - 1);         // clamp: loads safe, uses guarded
    int q = vc / QN, loc = vc - q * QN;
    const unsigned short* p = partial + (size_t)q * QN + loc + (size_t)sg * 16 * 8 * QN;
    unsigned short vals[16];
#pragma unroll
    for (int s = 0; s < 16; ++s) vals[s] = p[(size_t)s * 8 * QN];
    int c = 0;
#pragma unroll
    for (int s = 0; s < 16; ++s) c += vals[s];
    ssum[tid] = c;
    __syncthreads();
    if (tid >= 256) return;
    c = ssum[tid] + ssum[tid + 256] + ssum[tid + 512] + ssum[tid + 768];

    int lane = tid & 63;
    if (inb) {
        cnt[v] = c;
        dinv[v] = rsqrtf((float)c + 1.0f);    // +1 self loop
    }
    bool fl = inb && flag[v];
    unsigned long long mask = __ballot(fl);
    int myi = __popcll(mask & ((1ull << lane) - 1));
    int tot = __popcll(mask);
    int cc = fl ? c : 0;
    int incl = cc;
#pragma unroll
    for (int o = 1; o < 64; o <<= 1) {
        int t = __shfl_up(incl, o);
        if (lane >= o) incl += t;
    }
    int wsum = __shfl(incl, 63);
    int b0 = 0, b1 = 0;
    if (lane == 0) {
        if (tot)  b0 = atomicAdd(&counters[0], tot);
        if (wsum) b1 = atomicAdd(&counters[1], wsum);
    }
    b0 = __shfl(b0, 0);
    b1 = __shfl(b1, 0);
    if (fl) {
        int i = b0 + myi;
        nlist[i] = v;
        inv[v] = i;
        off[v] = b1 + (incl - cc);
    }
}

// ---------------- h(bf16) = F @ W via MFMA 16x16x32, B in registers --------
__global__ __launch_bounds__(256) void k_gemm(const float* __restrict__ F,
                                              const unsigned short* __restrict__ Wt,
                                              unsigned short* __restrict__ h, int n) {
    int tid = threadIdx.x;
    int wave = tid >> 6, lane = tid & 63;
    int l15 = lane & 15, kg = lane >> 4;

    const char* wb = (const char*)Wt;
    bf16x8 bfrag[4][4];
#pragma unroll
    for (int cb = 0; cb < 4; ++cb)
#pragma unroll
        for (int ks = 0; ks < 4; ++ks)
            bfrag[cb][ks] = *(const bf16x8*)(wb + (cb * 16 + l15) * 256 + ks * 64 + kg * 16);

    int row = blockIdx.x * 64 + wave * 16 + l15;
    int rowc = min(row, n - 1);                    // clamp; stores are guarded
    const float4* F4 = (const float4*)(F + (size_t)rowc * FIELD_DIM + kg * 8);

    f32x4 acc[4];
#pragma unroll
    for (int cb = 0; cb < 4; ++cb) acc[cb] = (f32x4){0.f, 0.f, 0.f, 0.f};

#pragma unroll
    for (int ks = 0; ks < 4; ++ks) {               // K = 32 per step
        float4 fa = F4[ks * 8];                    // k = 32ks + 8kg + 0..3
        float4 fb = F4[ks * 8 + 1];                // k = 32ks + 8kg + 4..7
        union { bf16x8 v; unsigned u[4]; } af;
        af.u[0] = pk2(fa.x, fa.y);
        af.u[1] = pk2(fa.z, fa.w);
        af.u[2] = pk2(fb.x, fb.y);
        af.u[3] = pk2(fb.z, fb.w);
#pragma unroll
        for (int cb = 0; cb < 4; ++cb)
            acc[cb] = __builtin_amdgcn_mfma_f32_16x16x32_bf16(af.v, bfrag[cb][ks],
                                                              acc[cb], 0, 0, 0);
    }
    // D: col = cb*16 + l15, row = blockbase + wave*16 + kg*4 + reg
    int rbase = blockIdx.x * 64 + wave * 16 + kg * 4;
#pragma unroll
    for (int r = 0; r < 4; ++r) {
        int orow = rbase + r;
        if (orow < n) {
            unsigned short* hp = h + (size_t)orow * 64 + l15;
#pragma unroll
            for (int cb = 0; cb < 4; ++cb) hp[cb * 16] = f2bf(acc[cb][r]);
        }
    }
}

// ---------------- fill in-edge lists for flagged destinations --------------
__global__ __launch_bounds__(256) void k_fill(const int* __restrict__ src,
                                              const int* __restrict__ dst,
                                              const unsigned char* __restrict__ flag,
                                              const int* __restrict__ off,
                                              int* __restrict__ cur,
                                              int* __restrict__ elist) {
    int i = blockIdx.x * blockDim.x + threadIdx.x;
    if (i >= N_EDGES / 4) return;
    int4 d4 = ((const int4*)dst)[i];
    int4 s4 = ((const int4*)src)[i];
#define FILL1(dd, ss) if (flag[dd]) { int p = atomicAdd(&cur[dd], 1); elist[off[dd] + p] = ss; }
    FILL1(d4.x, s4.x)
    FILL1(d4.y, s4.y)
    FILL1(d4.z, s4.z)
    FILL1(d4.w, s4.w)
#undef FILL1
}

// ---------------- pull: one wave per flagged node, 8-deep gather pipe ------
__global__ __launch_bounds__(256) void k_pull(const int* __restrict__ nlist,
                                              const int* __restrict__ counters,
                                              const int* __restrict__ cnt,
                                              const int* __restrict__ off,
                                              const int* __restrict__ elist,
                                              const unsigned short* __restrict__ h,
                                              const float* __restrict__ dinv,
                                              const float* __restrict__ bias,
                                              float* __restrict__ accc) {
    int t = blockIdx.x * blockDim.x + threadIdx.x;
    int wid = t >> 6;              // wave id = compact node index
    int lane = t & 63;
    if (wid >= counters[0]) return;
    int v = nlist[wid];
    float dvd = dinv[v];
    int deg = cnt[v];
    int base = off[v];
    float acc = bf2f(h[(size_t)v * 64 + lane]) * (dvd * dvd) + bias[lane];
    float acc2 = 0.f;
    int j = 0;
    for (; j + 7 < deg; j += 8) {
        int s0 = elist[base + j + 0];
        int s1 = elist[base + j + 1];
        int s2 = elist[base + j + 2];
        int s3 = elist[base + j + 3];
        int s4 = elist[base + j + 4];
        int s5 = elist[base + j + 5];
        int s6 = elist[base + j + 6];
        int s7 = elist[base + j + 7];
        float v0 = bf2f(h[(size_t)s0 * 64 + lane]);
        float v1 = bf2f(h[(size_t)s1 * 64 + lane]);
        float v2 = bf2f(h[(size_t)s2 * 64 + lane]);
        float v3 = bf2f(h[(size_t)s3 * 64 + lane]);
        float v4 = bf2f(h[(size_t)s4 * 64 + lane]);
        float v5 = bf2f(h[(size_t)s5 * 64 + lane]);
        float v6 = bf2f(h[(size_t)s6 * 64 + lane]);
        float v7 = bf2f(h[(size_t)s7 * 64 + lane]);
        float n0 = dinv[s0], n1 = dinv[s1], n2 = dinv[s2], n3 = dinv[s3];
        float n4 = dinv[s4], n5 = dinv[s5], n6 = dinv[s6], n7 = dinv[s7];
        acc  += v0 * (n0 * dvd);
        acc2 += v1 * (n1 * dvd);
        acc  += v2 * (n2 * dvd);
        acc2 += v3 * (n3 * dvd);
        acc  += v4 * (n4 * dvd);
        acc2 += v5 * (n5 * dvd);
        acc  += v6 * (n6 * dvd);
        acc2 += v7 * (n7 * dvd);
    }
    for (; j < deg; ++j) {
        int s0 = elist[base + j];
        acc += bf2f(h[(size_t)s0 * 64 + lane]) * (dinv[s0] * dvd);
    }
    accc[(size_t)wid * 64 + lane] = acc + acc2;
}

// ---------------- final gather: out[b] = accc[inv[x[b]]] -------------------
__global__ void k_gather(const int* __restrict__ x,
                         const int* __restrict__ inv,
                         const float* __restrict__ accc,
                         float* __restrict__ out) {
    int g = blockIdx.x * blockDim.x + threadIdx.x;   // [0, NX*64)
    if (g >= NX * 64) return;
    int v = x[g >> 6];
    out[g] = accc[(size_t)inv[v] * 64 + (g & 63)];
}

extern "C" void kernel_launch(void* const* d_in, const int* in_sizes, int n_in,
                              void* d_out, int out_size, void* d_ws, size_t ws_size,
                              hipStream_t stream) {
    const float* features = (const float*)d_in[0];
    const int*   edge     = (const int*)d_in[1];
    const float* W        = (const float*)d_in[2];
    const float* bias     = (const float*)d_in[3];
    const int*   x        = (const int*)d_in[4];
    float* out = (float*)d_out;

    char* ws = (char*)d_ws;
    unsigned short* h16      = (unsigned short*)(ws);            // 12,800,000 B
    unsigned short* partial  = (unsigned short*)(ws + 12800000); // 12,800,000 B
    int*            elist    = (int*)(ws + 12800000);            // overlay: live after k_reduce
    float*          accc     = (float*)(ws + 25600000);          //  4,194,304 B
    int*            cnt      = (int*)  (ws + 29794304);          //    400,000 B
    float*          dinv     = (float*)(ws + 30194304);          //    400,000 B
    int*            off      = (int*)  (ws + 30594304);          //    400,000 B
    int*            inv      = (int*)  (ws + 30994304);          //    400,000 B
    int*            nlist    = (int*)  (ws + 31394304);          //     65,536 B
    int*            cur      = (int*)  (ws + 31459840);          //    400,000 B
    int*            counters = (int*)  (ws + 31859840);          //         32 B
    unsigned char*  flag     = (unsigned char*)(ws + 31859872);  //    100,000 B
    unsigned short* Wt       = (unsigned short*)(ws + 31959872); //     16,384 B

    const int* esrc = edge;
    const int* edst = edge + N_EDGES;

    // one memset covers cur + counters + flag (contiguous)
    hipMemsetAsync(cur, 0, 500032, stream);

    k_init  <<<65, 256, 0, stream>>>(x, flag, W, Wt);
    k_hist  <<<8 * NSLICE, 256, 0, stream>>>(edst, partial);
    k_reduce<<<(N_NODES + 255) / 256, 1024, 0, stream>>>(partial, flag, cnt, dinv,
                                                         nlist, inv, off, counters);
    k_gemm  <<<(N_NODES + 63) / 64, 256, 0, stream>>>(features, Wt, h16, N_NODES);
    k_fill  <<<(N_EDGES / 4 + 255) / 256, 256, 0, stream>>>(esrc, edst, flag, off,
                                                            cur, elist);
    k_pull  <<<(NX * 64 + 255) / 256, 256, 0, stream>>>(nlist, counters, cnt, off,
                                                        elist, h16, dinv, bias, accc);
    k_gather<<<(NX * 64 + 255) / 256, 256, 0, stream>>>(x, inv, accc, out);
}

// Round 8
// 130.442 us; speedup vs baseline: 16.1240x; 1.2363x over previous
//
#include <hip/hip_runtime.h>

#define N_NODES   100000
#define FIELD_DIM 128
#define EMBED_DIM 64
#define N_EDGES   3200000
#define NX        16384   // BATCH * NUM_FIELDS

#define QN        12500   // nodes per histogram range (8 ranges)
#define NSLICE    64      // edge slices
#define SLICE_E   (N_EDGES / NSLICE)   // 50000

typedef short  bf16x8 __attribute__((ext_vector_type(8)));
typedef float  f32x4  __attribute__((ext_vector_type(4)));

__device__ __forceinline__ unsigned short f2bf(float x) {
    unsigned u = __float_as_uint(x);
    u += 0x7FFF + ((u >> 16) & 1);          // round-to-nearest-even
    return (unsigned short)(u >> 16);
}
__device__ __forceinline__ float bf2f(unsigned short b) {
    return __uint_as_float(((unsigned)b) << 16);
}
__device__ __forceinline__ unsigned pk2(float lo, float hi) {
    return (unsigned)f2bf(lo) | ((unsigned)f2bf(hi) << 16);
}

// ---------------- init: flag needed nodes (blocks 0..63) + W transpose -----
// Wt: bf16 Wt[c][k] (64 x 128), LINEAR layout, byte addr c*256 + k*2.
__global__ void k_init(const int* __restrict__ x, unsigned char* __restrict__ flag,
                       const float* __restrict__ W, unsigned short* __restrict__ Wt) {
    int b = blockIdx.x;
    if (b < 64) {
        int i = b * 256 + threadIdx.x;      // NX = 64*256 exactly
        flag[x[i]] = 1;                     // duplicate writes benign
    } else {
        for (int i = threadIdx.x; i < FIELD_DIM * EMBED_DIM; i += 256) {
            int k = i >> 6, c = i & 63;
            Wt[c * FIELD_DIM + k] = f2bf(W[i]);
        }
    }
}

// ---------------- degree histogram: LDS-privatized, 8 ranges x 64 slices ---
__global__ __launch_bounds__(256) void k_hist(const int* __restrict__ dst,
                                              unsigned short* __restrict__ partial) {
    __shared__ int hist[QN];                  // 50,000 B
    int tid = threadIdx.x;
    int q = blockIdx.x & 7, s = blockIdx.x >> 3;
    for (int i = tid; i < QN; i += 256) hist[i] = 0;
    __syncthreads();
    int lo = q * QN;
    const int4* dp = (const int4*)(dst + s * SLICE_E);
    for (int i = tid; i < SLICE_E / 4; i += 256) {
        int4 d = dp[i];
        int a;
        a = d.x - lo; if ((unsigned)a < QN) atomicAdd(&hist[a], 1);
        a = d.y - lo; if ((unsigned)a < QN) atomicAdd(&hist[a], 1);
        a = d.z - lo; if ((unsigned)a < QN) atomicAdd(&hist[a], 1);
        a = d.w - lo; if ((unsigned)a < QN) atomicAdd(&hist[a], 1);
    }
    __syncthreads();
    unsigned int* po = (unsigned int*)(partial + (size_t)blockIdx.x * QN);
    for (int i = tid; i < QN / 2; i += 256) {
        unsigned int v = ((unsigned int)hist[2 * i] & 0xFFFFu) |
                         ((unsigned int)hist[2 * i + 1] << 16);
        po[i] = v;
    }
}

// ---------------- reduce partials + dinv + compaction (1 atomic/block) -----
// 1024 thr/block: 4 slice-groups x 256 nodes for the partial sum.
// Compaction: per-wave ballot/scan -> LDS -> single packed u64 atomic by t0:
//   counters u64 = (edge_total << 32) | node_total.
__global__ __launch_bounds__(1024) void k_reduce(const unsigned short* __restrict__ partial,
                                                 const unsigned char* __restrict__ flag,
                                                 int* __restrict__ cnt,
                                                 float* __restrict__ dinv,
                                                 int* __restrict__ nlist,
                                                 int* __restrict__ inv,
                                                 int* __restrict__ off,
                                                 int* __restrict__ cur,
                                                 unsigned long long* __restrict__ counters) {
    __shared__ int ssum[1024];
    __shared__ int wtot[4], wedge[4], ptot[4], pedge[4];
    __shared__ unsigned int baseN, baseE;
    int tid = threadIdx.x;
    int nloc = tid & 255, sg = tid >> 8;      // 4 slice groups of 16 slices
    int v = blockIdx.x * 256 + nloc;
    bool inb = (v < N_NODES);
    int vc = inb ? v : (N_NODES - 1);         // clamp: loads safe, uses guarded
    int q = vc / QN, loc = vc - q * QN;
    const unsigned short* p = partial + (size_t)q * QN + loc + (size_t)sg * 16 * 8 * QN;
    unsigned short vals[16];
#pragma unroll
    for (int s = 0; s < 16; ++s) vals[s] = p[(size_t)s * 8 * QN];
    int c = 0;
#pragma unroll
    for (int s = 0; s < 16; ++s) c += vals[s];
    ssum[tid] = c;
    __syncthreads();

    bool act = (tid < 256);
    int lane = tid & 63;
    int w = tid >> 6;                         // wave id (0..3 when act)
    bool fl = false;
    int myi = 0, excl = 0;
    if (act) {                                // whole waves 0..3: uniform
        c = ssum[tid] + ssum[tid + 256] + ssum[tid + 512] + ssum[tid + 768];
        if (inb) {
            cnt[v] = c;
            dinv[v] = rsqrtf((float)c + 1.0f);    // +1 self loop
        }
        fl = inb && flag[v];
        unsigned long long mask = __ballot(fl);
        int cc = fl ? c : 0;
        int incl = cc;
#pragma unroll
        for (int o = 1; o < 64; o <<= 1) {
            int t = __shfl_up(incl, o);
            if (lane >= o) incl += t;
        }
        if (lane == 63) { wtot[w] = __popcll(mask); wedge[w] = incl; }
        myi = __popcll(mask & ((1ull << lane) - 1));
        excl = incl - cc;
    }
    __syncthreads();
    if (tid == 0) {
        int t0 = wtot[0], t1 = wtot[1], t2 = wtot[2], t3 = wtot[3];
        int e0 = wedge[0], e1 = wedge[1], e2 = wedge[2], e3 = wedge[3];
        ptot[0] = 0; ptot[1] = t0; ptot[2] = t0 + t1; ptot[3] = t0 + t1 + t2;
        pedge[0] = 0; pedge[1] = e0; pedge[2] = e0 + e1; pedge[3] = e0 + e1 + e2;
        int bt = t0 + t1 + t2 + t3;
        int be = e0 + e1 + e2 + e3;
        if (bt > 0) {
            unsigned long long add = ((unsigned long long)(unsigned)be << 32) |
                                     (unsigned long long)(unsigned)bt;
            unsigned long long old = atomicAdd(counters, add);
            baseN = (unsigned)(old & 0xFFFFFFFFull);
            baseE = (unsigned)(old >> 32);
        } else {
            baseN = 0; baseE = 0;
        }
    }
    __syncthreads();
    if (act && fl) {
        int i = (int)baseN + ptot[w] + myi;
        int o = (int)baseE + pedge[w] + excl;
        nlist[i] = v;
        inv[v] = i;
        off[v] = o;
        cur[v] = o;                           // fill claims slots directly from cur
    }
}

// ---------------- h(bf16) = F @ W via MFMA 16x16x32, B in registers --------
__global__ __launch_bounds__(256) void k_gemm(const float* __restrict__ F,
                                              const unsigned short* __restrict__ Wt,
                                              unsigned short* __restrict__ h, int n) {
    int tid = threadIdx.x;
    int wave = tid >> 6, lane = tid & 63;
    int l15 = lane & 15, kg = lane >> 4;

    const char* wb = (const char*)Wt;
    bf16x8 bfrag[4][4];
#pragma unroll
    for (int cb = 0; cb < 4; ++cb)
#pragma unroll
        for (int ks = 0; ks < 4; ++ks)
            bfrag[cb][ks] = *(const bf16x8*)(wb + (cb * 16 + l15) * 256 + ks * 64 + kg * 16);

    int row = blockIdx.x * 64 + wave * 16 + l15;
    int rowc = min(row, n - 1);                    // clamp; stores are guarded
    const float4* F4 = (const float4*)(F + (size_t)rowc * FIELD_DIM + kg * 8);

    f32x4 acc[4];
#pragma unroll
    for (int cb = 0; cb < 4; ++cb) acc[cb] = (f32x4){0.f, 0.f, 0.f, 0.f};

#pragma unroll
    for (int ks = 0; ks < 4; ++ks) {               // K = 32 per step
        float4 fa = F4[ks * 8];                    // k = 32ks + 8kg + 0..3
        float4 fb = F4[ks * 8 + 1];                // k = 32ks + 8kg + 4..7
        union { bf16x8 v; unsigned u[4]; } af;
        af.u[0] = pk2(fa.x, fa.y);
        af.u[1] = pk2(fa.z, fa.w);
        af.u[2] = pk2(fb.x, fb.y);
        af.u[3] = pk2(fb.z, fb.w);
#pragma unroll
        for (int cb = 0; cb < 4; ++cb)
            acc[cb] = __builtin_amdgcn_mfma_f32_16x16x32_bf16(af.v, bfrag[cb][ks],
                                                              acc[cb], 0, 0, 0);
    }
    // D: col = cb*16 + l15, row = blockbase + wave*16 + kg*4 + reg
    int rbase = blockIdx.x * 64 + wave * 16 + kg * 4;
#pragma unroll
    for (int r = 0; r < 4; ++r) {
        int orow = rbase + r;
        if (orow < n) {
            unsigned short* hp = h + (size_t)orow * 64 + l15;
#pragma unroll
            for (int cb = 0; cb < 4; ++cb) hp[cb * 16] = f2bf(acc[cb][r]);
        }
    }
}

// ---------------- fill in-edge lists: slot = atomicAdd(cur[dd]) ------------
__global__ __launch_bounds__(256) void k_fill(const int* __restrict__ src,
                                              const int* __restrict__ dst,
                                              const unsigned char* __restrict__ flag,
                                              int* __restrict__ cur,
                                              int* __restrict__ elist) {
    int i = blockIdx.x * blockDim.x + threadIdx.x;
    if (i >= N_EDGES / 4) return;
    int4 d4 = ((const int4*)dst)[i];
    int4 s4 = ((const int4*)src)[i];
#define FILL1(dd, ss) if (flag[dd]) { int p = atomicAdd(&cur[dd], 1); elist[p] = ss; }
    FILL1(d4.x, s4.x)
    FILL1(d4.y, s4.y)
    FILL1(d4.z, s4.z)
    FILL1(d4.w, s4.w)
#undef FILL1
}

// ---------------- pull: one wave per flagged node, 8-deep gather pipe ------
__global__ __launch_bounds__(256) void k_pull(const int* __restrict__ nlist,
                                              const int* __restrict__ counters,
                                              const int* __restrict__ cnt,
                                              const int* __restrict__ off,
                                              const int* __restrict__ elist,
                                              const unsigned short* __restrict__ h,
                                              const float* __restrict__ dinv,
                                              const float* __restrict__ bias,
                                              float* __restrict__ accc) {
    int t = blockIdx.x * blockDim.x + threadIdx.x;
    int wid = t >> 6;              // wave id = compact node index
    int lane = t & 63;
    if (wid >= counters[0]) return;   // low 32 bits of packed u64 = node count
    int v = nlist[wid];
    float dvd = dinv[v];
    int deg = cnt[v];
    int base = off[v];
    float acc = bf2f(h[(size_t)v * 64 + lane]) * (dvd * dvd) + bias[lane];
    float acc2 = 0.f;
    int j = 0;
    for (; j + 7 < deg; j += 8) {
        int s0 = elist[base + j + 0];
        int s1 = elist[base + j + 1];
        int s2 = elist[base + j + 2];
        int s3 = elist[base + j + 3];
        int s4 = elist[base + j + 4];
        int s5 = elist[base + j + 5];
        int s6 = elist[base + j + 6];
        int s7 = elist[base + j + 7];
        float v0 = bf2f(h[(size_t)s0 * 64 + lane]);
        float v1 = bf2f(h[(size_t)s1 * 64 + lane]);
        float v2 = bf2f(h[(size_t)s2 * 64 + lane]);
        float v3 = bf2f(h[(size_t)s3 * 64 + lane]);
        float v4 = bf2f(h[(size_t)s4 * 64 + lane]);
        float v5 = bf2f(h[(size_t)s5 * 64 + lane]);
        float v6 = bf2f(h[(size_t)s6 * 64 + lane]);
        float v7 = bf2f(h[(size_t)s7 * 64 + lane]);
        float n0 = dinv[s0], n1 = dinv[s1], n2 = dinv[s2], n3 = dinv[s3];
        float n4 = dinv[s4], n5 = dinv[s5], n6 = dinv[s6], n7 = dinv[s7];
        acc  += v0 * (n0 * dvd);
        acc2 += v1 * (n1 * dvd);
        acc  += v2 * (n2 * dvd);
        acc2 += v3 * (n3 * dvd);
        acc  += v4 * (n4 * dvd);
        acc2 += v5 * (n5 * dvd);
        acc  += v6 * (n6 * dvd);
        acc2 += v7 * (n7 * dvd);
    }
    for (; j < deg; ++j) {
        int s0 = elist[base + j];
        acc += bf2f(h[(size_t)s0 * 64 + lane]) * (dinv[s0] * dvd);
    }
    accc[(size_t)wid * 64 + lane] = acc + acc2;
}

// ---------------- final gather: out[b] = accc[inv[x[b]]] -------------------
__global__ void k_gather(const int* __restrict__ x,
                         const int* __restrict__ inv,
                         const float* __restrict__ accc,
                         float* __restrict__ out) {
    int g = blockIdx.x * blockDim.x + threadIdx.x;   // [0, NX*64)
    if (g >= NX * 64) return;
    int v = x[g >> 6];
    out[g] = accc[(size_t)inv[v] * 64 + (g & 63)];
}

extern "C" void kernel_launch(void* const* d_in, const int* in_sizes, int n_in,
                              void* d_out, int out_size, void* d_ws, size_t ws_size,
                              hipStream_t stream) {
    const float* features = (const float*)d_in[0];
    const int*   edge     = (const int*)d_in[1];
    const float* W        = (const float*)d_in[2];
    const float* bias     = (const float*)d_in[3];
    const int*   x        = (const int*)d_in[4];
    float* out = (float*)d_out;

    char* ws = (char*)d_ws;
    unsigned short* h16      = (unsigned short*)(ws);            // 12,800,000 B
    unsigned short* partial  = (unsigned short*)(ws + 12800000); // 12,800,000 B
    int*            elist    = (int*)(ws + 12800000);            // overlay: live after k_reduce
    float*          accc     = (float*)(ws + 25600000);          //  4,194,304 B
    int*            cnt      = (int*)  (ws + 29794304);          //    400,000 B
    float*          dinv     = (float*)(ws + 30194304);          //    400,000 B
    int*            off      = (int*)  (ws + 30594304);          //    400,000 B
    int*            inv      = (int*)  (ws + 30994304);          //    400,000 B
    int*            nlist    = (int*)  (ws + 31394304);          //     65,536 B
    int*            cur      = (int*)  (ws + 31459840);          //    400,000 B
    unsigned long long* counters = (unsigned long long*)(ws + 31859840); // 32 B
    unsigned char*  flag     = (unsigned char*)(ws + 31859872);  //    100,000 B
    unsigned short* Wt       = (unsigned short*)(ws + 31959872); //     16,384 B

    const int* esrc = edge;
    const int* edst = edge + N_EDGES;

    // one memset covers counters + flag (contiguous); cur is seeded by k_reduce
    hipMemsetAsync(counters, 0, 100032, stream);

    k_init  <<<65, 256, 0, stream>>>(x, flag, W, Wt);
    k_hist  <<<8 * NSLICE, 256, 0, stream>>>(edst, partial);
    k_reduce<<<(N_NODES + 255) / 256, 1024, 0, stream>>>(partial, flag, cnt, dinv,
                                                         nlist, inv, off, cur, counters);
    k_gemm  <<<(N_NODES + 63) / 64, 256, 0, stream>>>(features, Wt, h16, N_NODES);
    k_fill  <<<(N_EDGES / 4 + 255) / 256, 256, 0, stream>>>(esrc, edst, flag, cur, elist);
    k_pull  <<<(NX * 64 + 255) / 256, 256, 0, stream>>>(nlist, (const int*)counters,
                                                        cnt, off, elist, h16, dinv,
                                                        bias, accc);
    k_gather<<<(NX * 64 + 255) / 256, 256, 0, stream>>>(x, inv, accc, out);
}

// Round 9
// 128.764 us; speedup vs baseline: 16.3341x; 1.0130x over previous
//
#include <hip/hip_runtime.h>

#define N_NODES   100000
#define FIELD_DIM 128
#define EMBED_DIM 64
#define N_EDGES   3200000
#define NX        16384   // BATCH * NUM_FIELDS

#define QN        12500   // nodes per histogram range (8 ranges)
#define NSLICE    64      // edge slices
#define SLICE_E   (N_EDGES / NSLICE)   // 50000

typedef short  bf16x8 __attribute__((ext_vector_type(8)));
typedef float  f32x4  __attribute__((ext_vector_type(4)));

__device__ __forceinline__ unsigned short f2bf(float x) {
    unsigned u = __float_as_uint(x);
    u += 0x7FFF + ((u >> 16) & 1);          // round-to-nearest-even
    return (unsigned short)(u >> 16);
}
__device__ __forceinline__ float bf2f(unsigned short b) {
    return __uint_as_float(((unsigned)b) << 16);
}
__device__ __forceinline__ unsigned pk2(float lo, float hi) {
    return (unsigned)f2bf(lo) | ((unsigned)f2bf(hi) << 16);
}

// ---------------- zero counters + flag + bitmap (112544 B, one range) ------
__global__ void k_zero(float4* __restrict__ z4) {
    int i = blockIdx.x * blockDim.x + threadIdx.x;
    if (i < 7034) z4[i] = make_float4(0.f, 0.f, 0.f, 0.f);
}

// ---------------- init: flag needed nodes (blocks 0..63) + W transpose -----
// Wt: bf16 Wt[c][k] (64 x 128), LINEAR layout, byte addr c*256 + k*2.
__global__ void k_init(const int* __restrict__ x, unsigned char* __restrict__ flag,
                       unsigned int* __restrict__ bits,
                       const float* __restrict__ W, unsigned short* __restrict__ Wt) {
    int b = blockIdx.x;
    if (b < 64) {
        int i = b * 256 + threadIdx.x;      // NX = 64*256 exactly
        int v = x[i];
        flag[v] = 1;                        // duplicate writes benign
        atomicOr(&bits[v >> 5], 1u << (v & 31));
    } else {
        for (int i = threadIdx.x; i < FIELD_DIM * EMBED_DIM; i += 256) {
            int k = i >> 6, c = i & 63;
            Wt[c * FIELD_DIM + k] = f2bf(W[i]);
        }
    }
}

// ---------------- degree histogram: LDS-privatized, 8 ranges x 64 slices ---
__global__ __launch_bounds__(256) void k_hist(const int* __restrict__ dst,
                                              unsigned short* __restrict__ partial) {
    __shared__ int hist[QN];                  // 50,000 B
    int tid = threadIdx.x;
    int q = blockIdx.x & 7, s = blockIdx.x >> 3;
    for (int i = tid; i < QN; i += 256) hist[i] = 0;
    __syncthreads();
    int lo = q * QN;
    const int4* dp = (const int4*)(dst + s * SLICE_E);
    for (int i = tid; i < SLICE_E / 4; i += 256) {
        int4 d = dp[i];
        int a;
        a = d.x - lo; if ((unsigned)a < QN) atomicAdd(&hist[a], 1);
        a = d.y - lo; if ((unsigned)a < QN) atomicAdd(&hist[a], 1);
        a = d.z - lo; if ((unsigned)a < QN) atomicAdd(&hist[a], 1);
        a = d.w - lo; if ((unsigned)a < QN) atomicAdd(&hist[a], 1);
    }
    __syncthreads();
    unsigned int* po = (unsigned int*)(partial + (size_t)blockIdx.x * QN);
    for (int i = tid; i < QN / 2; i += 256) {
        unsigned int v = ((unsigned int)hist[2 * i] & 0xFFFFu) |
                         ((unsigned int)hist[2 * i + 1] << 16);
        po[i] = v;
    }
}

// ---------------- reduce partials + dinv + compaction (1 atomic/block) -----
// 1024 thr/block: 4 slice-groups x 256 nodes for the partial sum.
// Compaction: per-wave ballot/scan -> LDS -> single packed u64 atomic by t0:
//   counters u64 = (edge_total << 32) | node_total.
__global__ __launch_bounds__(1024) void k_reduce(const unsigned short* __restrict__ partial,
                                                 const unsigned char* __restrict__ flag,
                                                 int* __restrict__ cnt,
                                                 float* __restrict__ dinv,
                                                 int* __restrict__ nlist,
                                                 int* __restrict__ inv,
                                                 int* __restrict__ off,
                                                 int* __restrict__ cur,
                                                 unsigned long long* __restrict__ counters) {
    __shared__ int ssum[1024];
    __shared__ int wtot[4], wedge[4], ptot[4], pedge[4];
    __shared__ unsigned int baseN, baseE;
    int tid = threadIdx.x;
    int nloc = tid & 255, sg = tid >> 8;      // 4 slice groups of 16 slices
    int v = blockIdx.x * 256 + nloc;
    bool inb = (v < N_NODES);
    int vc = inb ? v : (N_NODES - 1);         // clamp: loads safe, uses guarded
    int q = vc / QN, loc = vc - q * QN;
    const unsigned short* p = partial + (size_t)q * QN + loc + (size_t)sg * 16 * 8 * QN;
    unsigned short vals[16];
#pragma unroll
    for (int s = 0; s < 16; ++s) vals[s] = p[(size_t)s * 8 * QN];
    int c = 0;
#pragma unroll
    for (int s = 0; s < 16; ++s) c += vals[s];
    ssum[tid] = c;
    __syncthreads();

    bool act = (tid < 256);
    int lane = tid & 63;
    int w = tid >> 6;                         // wave id (0..3 when act)
    bool fl = false;
    int myi = 0, excl = 0;
    if (act) {                                // whole waves 0..3: uniform
        c = ssum[tid] + ssum[tid + 256] + ssum[tid + 512] + ssum[tid + 768];
        if (inb) {
            cnt[v] = c;
            dinv[v] = rsqrtf((float)c + 1.0f);    // +1 self loop
        }
        fl = inb && flag[v];
        unsigned long long mask = __ballot(fl);
        int cc = fl ? c : 0;
        int incl = cc;
#pragma unroll
        for (int o = 1; o < 64; o <<= 1) {
            int t = __shfl_up(incl, o);
            if (lane >= o) incl += t;
        }
        if (lane == 63) { wtot[w] = __popcll(mask); wedge[w] = incl; }
        myi = __popcll(mask & ((1ull << lane) - 1));
        excl = incl - cc;
    }
    __syncthreads();
    if (tid == 0) {
        int t0 = wtot[0], t1 = wtot[1], t2 = wtot[2], t3 = wtot[3];
        int e0 = wedge[0], e1 = wedge[1], e2 = wedge[2], e3 = wedge[3];
        ptot[0] = 0; ptot[1] = t0; ptot[2] = t0 + t1; ptot[3] = t0 + t1 + t2;
        pedge[0] = 0; pedge[1] = e0; pedge[2] = e0 + e1; pedge[3] = e0 + e1 + e2;
        int bt = t0 + t1 + t2 + t3;
        int be = e0 + e1 + e2 + e3;
        if (bt > 0) {
            unsigned long long add = ((unsigned long long)(unsigned)be << 32) |
                                     (unsigned long long)(unsigned)bt;
            unsigned long long old = atomicAdd(counters, add);
            baseN = (unsigned)(old & 0xFFFFFFFFull);
            baseE = (unsigned)(old >> 32);
        } else {
            baseN = 0; baseE = 0;
        }
    }
    __syncthreads();
    if (act && fl) {
        int i = (int)baseN + ptot[w] + myi;
        int o = (int)baseE + pedge[w] + excl;
        nlist[i] = v;
        inv[v] = i;
        off[v] = o;
        cur[v] = o;                           // fill claims slots directly from cur
    }
}

// ---------------- h(bf16) = F @ W via MFMA 16x16x32, B in registers --------
__global__ __launch_bounds__(256) void k_gemm(const float* __restrict__ F,
                                              const unsigned short* __restrict__ Wt,
                                              unsigned short* __restrict__ h, int n) {
    int tid = threadIdx.x;
    int wave = tid >> 6, lane = tid & 63;
    int l15 = lane & 15, kg = lane >> 4;

    const char* wb = (const char*)Wt;
    bf16x8 bfrag[4][4];
#pragma unroll
    for (int cb = 0; cb < 4; ++cb)
#pragma unroll
        for (int ks = 0; ks < 4; ++ks)
            bfrag[cb][ks] = *(const bf16x8*)(wb + (cb * 16 + l15) * 256 + ks * 64 + kg * 16);

    int row = blockIdx.x * 64 + wave * 16 + l15;
    int rowc = min(row, n - 1);                    // clamp; stores are guarded
    const float4* F4 = (const float4*)(F + (size_t)rowc * FIELD_DIM + kg * 8);

    f32x4 acc[4];
#pragma unroll
    for (int cb = 0; cb < 4; ++cb) acc[cb] = (f32x4){0.f, 0.f, 0.f, 0.f};

#pragma unroll
    for (int ks = 0; ks < 4; ++ks) {               // K = 32 per step
        float4 fa = F4[ks * 8];                    // k = 32ks + 8kg + 0..3
        float4 fb = F4[ks * 8 + 1];                // k = 32ks + 8kg + 4..7
        union { bf16x8 v; unsigned u[4]; } af;
        af.u[0] = pk2(fa.x, fa.y);
        af.u[1] = pk2(fa.z, fa.w);
        af.u[2] = pk2(fb.x, fb.y);
        af.u[3] = pk2(fb.z, fb.w);
#pragma unroll
        for (int cb = 0; cb < 4; ++cb)
            acc[cb] = __builtin_amdgcn_mfma_f32_16x16x32_bf16(af.v, bfrag[cb][ks],
                                                              acc[cb], 0, 0, 0);
    }
    // D: col = cb*16 + l15, row = blockbase + wave*16 + kg*4 + reg
    int rbase = blockIdx.x * 64 + wave * 16 + kg * 4;
#pragma unroll
    for (int r = 0; r < 4; ++r) {
        int orow = rbase + r;
        if (orow < n) {
            unsigned short* hp = h + (size_t)orow * 64 + l15;
#pragma unroll
            for (int cb = 0; cb < 4; ++cb) hp[cb * 16] = f2bf(acc[cb][r]);
        }
    }
}

// ---------------- fill in-edge lists: bitmap flag check + cur atomic -------
__global__ __launch_bounds__(256) void k_fill(const int* __restrict__ src,
                                              const int* __restrict__ dst,
                                              const unsigned int* __restrict__ bits,
                                              int* __restrict__ cur,
                                              int* __restrict__ elist) {
    int i = blockIdx.x * blockDim.x + threadIdx.x;
    if (i >= N_EDGES / 4) return;
    int4 d4 = ((const int4*)dst)[i];
    int4 s4 = ((const int4*)src)[i];
#define FILL1(dd, ss) if ((bits[(unsigned)(dd) >> 5] >> ((dd) & 31)) & 1u) \
    { int p = atomicAdd(&cur[dd], 1); elist[p] = ss; }
    FILL1(d4.x, s4.x)
    FILL1(d4.y, s4.y)
    FILL1(d4.z, s4.z)
    FILL1(d4.w, s4.w)
#undef FILL1
}

// ---------------- pull: one wave per flagged node, 8-deep gather pipe ------
__global__ __launch_bounds__(256) void k_pull(const int* __restrict__ nlist,
                                              const int* __restrict__ counters,
                                              const int* __restrict__ cnt,
                                              const int* __restrict__ off,
                                              const int* __restrict__ elist,
                                              const unsigned short* __restrict__ h,
                                              const float* __restrict__ dinv,
                                              const float* __restrict__ bias,
                                              float* __restrict__ accc) {
    int t = blockIdx.x * blockDim.x + threadIdx.x;
    int wid = t >> 6;              // wave id = compact node index
    int lane = t & 63;
    if (wid >= counters[0]) return;   // low 32 bits of packed u64 = node count
    int v = nlist[wid];
    float dvd = dinv[v];
    int deg = cnt[v];
    int base = off[v];
    float acc = bf2f(h[(size_t)v * 64 + lane]) * (dvd * dvd) + bias[lane];
    float acc2 = 0.f;
    int j = 0;
    for (; j + 7 < deg; j += 8) {
        int s0 = elist[base + j + 0];
        int s1 = elist[base + j + 1];
        int s2 = elist[base + j + 2];
        int s3 = elist[base + j + 3];
        int s4 = elist[base + j + 4];
        int s5 = elist[base + j + 5];
        int s6 = elist[base + j + 6];
        int s7 = elist[base + j + 7];
        float v0 = bf2f(h[(size_t)s0 * 64 + lane]);
        float v1 = bf2f(h[(size_t)s1 * 64 + lane]);
        float v2 = bf2f(h[(size_t)s2 * 64 + lane]);
        float v3 = bf2f(h[(size_t)s3 * 64 + lane]);
        float v4 = bf2f(h[(size_t)s4 * 64 + lane]);
        float v5 = bf2f(h[(size_t)s5 * 64 + lane]);
        float v6 = bf2f(h[(size_t)s6 * 64 + lane]);
        float v7 = bf2f(h[(size_t)s7 * 64 + lane]);
        float n0 = dinv[s0], n1 = dinv[s1], n2 = dinv[s2], n3 = dinv[s3];
        float n4 = dinv[s4], n5 = dinv[s5], n6 = dinv[s6], n7 = dinv[s7];
        acc  += v0 * (n0 * dvd);
        acc2 += v1 * (n1 * dvd);
        acc  += v2 * (n2 * dvd);
        acc2 += v3 * (n3 * dvd);
        acc  += v4 * (n4 * dvd);
        acc2 += v5 * (n5 * dvd);
        acc  += v6 * (n6 * dvd);
        acc2 += v7 * (n7 * dvd);
    }
    for (; j < deg; ++j) {
        int s0 = elist[base + j];
        acc += bf2f(h[(size_t)s0 * 64 + lane]) * (dinv[s0] * dvd);
    }
    accc[(size_t)wid * 64 + lane] = acc + acc2;
}

// ---------------- final gather: out[b] = accc[inv[x[b]]] -------------------
__global__ void k_gather(const int* __restrict__ x,
                         const int* __restrict__ inv,
                         const float* __restrict__ accc,
                         float* __restrict__ out) {
    int g = blockIdx.x * blockDim.x + threadIdx.x;   // [0, NX*64)
    if (g >= NX * 64) return;
    int v = x[g >> 6];
    out[g] = accc[(size_t)inv[v] * 64 + (g & 63)];
}

extern "C" void kernel_launch(void* const* d_in, const int* in_sizes, int n_in,
                              void* d_out, int out_size, void* d_ws, size_t ws_size,
                              hipStream_t stream) {
    const float* features = (const float*)d_in[0];
    const int*   edge     = (const int*)d_in[1];
    const float* W        = (const float*)d_in[2];
    const float* bias     = (const float*)d_in[3];
    const int*   x        = (const int*)d_in[4];
    float* out = (float*)d_out;

    char* ws = (char*)d_ws;
    unsigned short* h16      = (unsigned short*)(ws);            // 12,800,000 B
    unsigned short* partial  = (unsigned short*)(ws + 12800000); // 12,800,000 B
    int*            elist    = (int*)(ws + 12800000);            // overlay: live after k_reduce
    float*          accc     = (float*)(ws + 25600000);          //  4,194,304 B
    int*            cnt      = (int*)  (ws + 29794304);          //    400,000 B
    float*          dinv     = (float*)(ws + 30194304);          //    400,000 B
    int*            off      = (int*)  (ws + 30594304);          //    400,000 B
    int*            inv      = (int*)  (ws + 30994304);          //    400,000 B
    int*            nlist    = (int*)  (ws + 31394304);          //     65,536 B
    int*            cur      = (int*)  (ws + 31459840);          //    400,000 B
    unsigned long long* counters = (unsigned long long*)(ws + 31859840); // 32 B
    unsigned char*  flag     = (unsigned char*)(ws + 31859872);  //    100,000 B
    unsigned int*   bits     = (unsigned int*) (ws + 31959872);  //     12,512 B
    unsigned short* Wt       = (unsigned short*)(ws + 31972384); //     16,384 B
    // zero range: counters..bits end = 31859840 .. 31972384 = 112,544 B = 7034 float4

    const int* esrc = edge;
    const int* edst = edge + N_EDGES;

    k_zero  <<<28, 256, 0, stream>>>((float4*)(ws + 31859840));
    k_init  <<<65, 256, 0, stream>>>(x, flag, bits, W, Wt);
    k_hist  <<<8 * NSLICE, 256, 0, stream>>>(edst, partial);
    k_reduce<<<(N_NODES + 255) / 256, 1024, 0, stream>>>(partial, flag, cnt, dinv,
                                                         nlist, inv, off, cur, counters);
    k_gemm  <<<(N_NODES + 63) / 64, 256, 0, stream>>>(features, Wt, h16, N_NODES);
    k_fill  <<<(N_EDGES / 4 + 255) / 256, 256, 0, stream>>>(esrc, edst, bits, cur, elist);
    k_pull  <<<(NX * 64 + 255) / 256, 256, 0, stream>>>(nlist, (const int*)counters,
                                                        cnt, off, elist, h16, dinv,
                                                        bias, accc);
    k_gather<<<(NX * 64 + 255) / 256, 256, 0, stream>>>(x, inv, accc, out);
}

// Round 10
// 122.383 us; speedup vs baseline: 17.1858x; 1.0521x over previous
//
#include <hip/hip_runtime.h>

#define N_NODES   100000
#define FIELD_DIM 128
#define EMBED_DIM 64
#define N_EDGES   3200000
#define NX        16384   // BATCH * NUM_FIELDS

#define NRANGE    4
#define RN        25000   // nodes per histogram range
#define RNH       12500   // packed u32 bins per range
#define NSLICE    64      // edge slices
#define SLICE_E   (N_EDGES / NSLICE)   // 50000 (< 65536: u16-safe per slice)
#define FILLB     (N_EDGES / 4 / 256)  // 3125 fill blocks (exact)
#define GEMMB     ((N_NODES + 63) / 64) // 1563 gemm blocks

typedef short  bf16x8 __attribute__((ext_vector_type(8)));
typedef float  f32x4  __attribute__((ext_vector_type(4)));

__device__ __forceinline__ unsigned short f2bf(float x) {
    unsigned u = __float_as_uint(x);
    u += 0x7FFF + ((u >> 16) & 1);          // round-to-nearest-even
    return (unsigned short)(u >> 16);
}
__device__ __forceinline__ float bf2f(unsigned short b) {
    return __uint_as_float(((unsigned)b) << 16);
}
__device__ __forceinline__ unsigned pk2(float lo, float hi) {
    return (unsigned)f2bf(lo) | ((unsigned)f2bf(hi) << 16);
}

// ---------------- zero counters + bitmap (12544 B = 784 float4) ------------
__global__ void k_zero(float4* __restrict__ z4) {
    int i = blockIdx.x * blockDim.x + threadIdx.x;
    if (i < 784) z4[i] = make_float4(0.f, 0.f, 0.f, 0.f);
}

// ---------------- init: bitmap of needed nodes (blocks 0..63) + W^T --------
__global__ void k_init(const int* __restrict__ x, unsigned int* __restrict__ bits,
                       const float* __restrict__ W, unsigned short* __restrict__ Wt) {
    int b = blockIdx.x;
    if (b < 64) {
        int i = b * 256 + threadIdx.x;      // NX = 64*256 exactly
        int v = x[i];
        atomicOr(&bits[v >> 5], 1u << (v & 31));
    } else {
        for (int i = threadIdx.x; i < FIELD_DIM * EMBED_DIM; i += 256) {
            int k = i >> 6, c = i & 63;
            Wt[c * FIELD_DIM + k] = f2bf(W[i]);
        }
    }
}

// ---------------- degree histogram: packed-u16 LDS, 4 ranges x 64 slices ---
// grid 256 = (s<<2)|q. Per-slice per-bin count <= 50000 < 2^16.
__global__ __launch_bounds__(256) void k_hist(const int* __restrict__ dst,
                                              unsigned int* __restrict__ partial32) {
    __shared__ unsigned int hist[RNH];        // 50,000 B (2 bins per u32)
    int tid = threadIdx.x;
    int q = blockIdx.x & 3, s = blockIdx.x >> 2;
    for (int i = tid; i < RNH; i += 256) hist[i] = 0;
    __syncthreads();
    int lo = q * RN;
    const int4* dp = (const int4*)(dst + s * SLICE_E);
    for (int i = tid; i < SLICE_E / 4; i += 256) {
        int4 d = dp[i];
        int a;
        a = d.x - lo; if ((unsigned)a < RN) atomicAdd(&hist[a >> 1], 1u << ((a & 1) << 4));
        a = d.y - lo; if ((unsigned)a < RN) atomicAdd(&hist[a >> 1], 1u << ((a & 1) << 4));
        a = d.z - lo; if ((unsigned)a < RN) atomicAdd(&hist[a >> 1], 1u << ((a & 1) << 4));
        a = d.w - lo; if ((unsigned)a < RN) atomicAdd(&hist[a >> 1], 1u << ((a & 1) << 4));
    }
    __syncthreads();
    unsigned int* po = partial32 + (size_t)blockIdx.x * RNH;
    for (int i = tid; i < RNH; i += 256) po[i] = hist[i];
}

// ---------------- reduce partials + dinv + compaction (1 atomic/block) -----
// 256 thr/block, thread = node. 64 slice loads in 4 register batches of 16.
__global__ __launch_bounds__(256) void k_reduce(const unsigned int* __restrict__ partial32,
                                                const unsigned int* __restrict__ bits,
                                                int* __restrict__ cnt,
                                                float* __restrict__ dinv,
                                                int* __restrict__ nlist,
                                                int* __restrict__ inv,
                                                int* __restrict__ off,
                                                int* __restrict__ cur,
                                                unsigned long long* __restrict__ counters) {
    __shared__ int wtot[4], wedge[4], ptot[4], pedge[4];
    __shared__ unsigned int baseN, baseE;
    int tid = threadIdx.x;
    int v = blockIdx.x * 256 + tid;
    bool inb = (v < N_NODES);
    int vc = inb ? v : (N_NODES - 1);
    int q = vc / RN, loc = vc - q * RN;
    int i2 = loc >> 1, sh = (loc & 1) << 4;
    const unsigned int* p = partial32 + (size_t)q * RNH + i2;
    int c = 0;
#pragma unroll
    for (int sb = 0; sb < 4; ++sb) {
        unsigned int vals[16];
#pragma unroll
        for (int s = 0; s < 16; ++s) vals[s] = p[(size_t)(sb * 16 + s) * (NRANGE * RNH)];
#pragma unroll
        for (int s = 0; s < 16; ++s) c += (int)((vals[s] >> sh) & 0xFFFFu);
    }
    if (inb) {
        cnt[v] = c;
        dinv[v] = rsqrtf((float)c + 1.0f);    // +1 self loop
    }
    bool fl = inb && ((bits[v >> 5] >> (v & 31)) & 1u);
    int lane = tid & 63;
    int w = tid >> 6;
    unsigned long long mask = __ballot(fl);
    int cc = fl ? c : 0;
    int incl = cc;
#pragma unroll
    for (int o = 1; o < 64; o <<= 1) {
        int t = __shfl_up(incl, o);
        if (lane >= o) incl += t;
    }
    if (lane == 63) { wtot[w] = __popcll(mask); wedge[w] = incl; }
    int myi = __popcll(mask & ((1ull << lane) - 1));
    int excl = incl - cc;
    __syncthreads();
    if (tid == 0) {
        int t0 = wtot[0], t1 = wtot[1], t2 = wtot[2], t3 = wtot[3];
        int e0 = wedge[0], e1 = wedge[1], e2 = wedge[2], e3 = wedge[3];
        ptot[0] = 0; ptot[1] = t0; ptot[2] = t0 + t1; ptot[3] = t0 + t1 + t2;
        pedge[0] = 0; pedge[1] = e0; pedge[2] = e0 + e1; pedge[3] = e0 + e1 + e2;
        int bt = t0 + t1 + t2 + t3;
        int be = e0 + e1 + e2 + e3;
        if (bt > 0) {
            unsigned long long add = ((unsigned long long)(unsigned)be << 32) |
                                     (unsigned long long)(unsigned)bt;
            unsigned long long old = atomicAdd(counters, add);
            baseN = (unsigned)(old & 0xFFFFFFFFull);
            baseE = (unsigned)(old >> 32);
        } else {
            baseN = 0; baseE = 0;
        }
    }
    __syncthreads();
    if (fl) {
        int i = (int)baseN + ptot[w] + myi;
        int o = (int)baseE + pedge[w] + excl;
        nlist[i] = v;
        inv[v] = i;
        off[v] = o;
        cur[v] = o;                           // fill claims slots directly from cur
    }
}

// ---------------- fused: fill (blocks 0..3124) + MFMA gemm (rest) ----------
__global__ __launch_bounds__(256) void k_fillgemm(const int* __restrict__ src,
                                                  const int* __restrict__ dst,
                                                  const unsigned int* __restrict__ bits,
                                                  int* __restrict__ cur,
                                                  int* __restrict__ elist,
                                                  const float* __restrict__ F,
                                                  const unsigned short* __restrict__ Wt,
                                                  unsigned short* __restrict__ h) {
    if (blockIdx.x < FILLB) {
        // ---- fill: bitmap check + cur atomic; 3125*256*4 = N_EDGES exactly
        int i = blockIdx.x * 256 + threadIdx.x;
        int4 d4 = ((const int4*)dst)[i];
        int4 s4 = ((const int4*)src)[i];
#define FILL1(dd, ss) if ((bits[(unsigned)(dd) >> 5] >> ((dd) & 31)) & 1u) \
        { int p = atomicAdd(&cur[dd], 1); elist[p] = ss; }
        FILL1(d4.x, s4.x)
        FILL1(d4.y, s4.y)
        FILL1(d4.z, s4.z)
        FILL1(d4.w, s4.w)
#undef FILL1
        return;
    }
    // ---- gemm: h(bf16) = F @ W, MFMA 16x16x32, B held in registers
    int gb = blockIdx.x - FILLB;
    int tid = threadIdx.x;
    int wave = tid >> 6, lane = tid & 63;
    int l15 = lane & 15, kg = lane >> 4;

    const char* wb = (const char*)Wt;
    bf16x8 bfrag[4][4];
#pragma unroll
    for (int cb = 0; cb < 4; ++cb)
#pragma unroll
        for (int ks = 0; ks < 4; ++ks)
            bfrag[cb][ks] = *(const bf16x8*)(wb + (cb * 16 + l15) * 256 + ks * 64 + kg * 16);

    int row = gb * 64 + wave * 16 + l15;
    int rowc = min(row, N_NODES - 1);              // clamp; stores are guarded
    const float4* F4 = (const float4*)(F + (size_t)rowc * FIELD_DIM + kg * 8);

    f32x4 acc[4];
#pragma unroll
    for (int cb = 0; cb < 4; ++cb) acc[cb] = (f32x4){0.f, 0.f, 0.f, 0.f};

#pragma unroll
    for (int ks = 0; ks < 4; ++ks) {               // K = 32 per step
        float4 fa = F4[ks * 8];                    // k = 32ks + 8kg + 0..3
        float4 fb = F4[ks * 8 + 1];                // k = 32ks + 8kg + 4..7
        union { bf16x8 v; unsigned u[4]; } af;
        af.u[0] = pk2(fa.x, fa.y);
        af.u[1] = pk2(fa.z, fa.w);
        af.u[2] = pk2(fb.x, fb.y);
        af.u[3] = pk2(fb.z, fb.w);
#pragma unroll
        for (int cb = 0; cb < 4; ++cb)
            acc[cb] = __builtin_amdgcn_mfma_f32_16x16x32_bf16(af.v, bfrag[cb][ks],
                                                              acc[cb], 0, 0, 0);
    }
    int rbase = gb * 64 + wave * 16 + kg * 4;
#pragma unroll
    for (int r = 0; r < 4; ++r) {
        int orow = rbase + r;
        if (orow < N_NODES) {
            unsigned short* hp = h + (size_t)orow * 64 + l15;
#pragma unroll
            for (int cb = 0; cb < 4; ++cb) hp[cb * 16] = f2bf(acc[cb][r]);
        }
    }
}

// ---------------- pull: one wave per flagged node, 8-deep gather pipe ------
__global__ __launch_bounds__(256) void k_pull(const int* __restrict__ nlist,
                                              const int* __restrict__ counters,
                                              const int* __restrict__ cnt,
                                              const int* __restrict__ off,
                                              const int* __restrict__ elist,
                                              const unsigned short* __restrict__ h,
                                              const float* __restrict__ dinv,
                                              const float* __restrict__ bias,
                                              float* __restrict__ accc) {
    int t = blockIdx.x * blockDim.x + threadIdx.x;
    int wid = t >> 6;              // wave id = compact node index
    int lane = t & 63;
    if (wid >= counters[0]) return;   // low 32 bits of packed u64 = node count
    int v = nlist[wid];
    float dvd = dinv[v];
    int deg = cnt[v];
    int base = off[v];
    float acc = bf2f(h[(size_t)v * 64 + lane]) * (dvd * dvd) + bias[lane];
    float acc2 = 0.f;
    int j = 0;
    for (; j + 7 < deg; j += 8) {
        int s0 = elist[base + j + 0];
        int s1 = elist[base + j + 1];
        int s2 = elist[base + j + 2];
        int s3 = elist[base + j + 3];
        int s4 = elist[base + j + 4];
        int s5 = elist[base + j + 5];
        int s6 = elist[base + j + 6];
        int s7 = elist[base + j + 7];
        float v0 = bf2f(h[(size_t)s0 * 64 + lane]);
        float v1 = bf2f(h[(size_t)s1 * 64 + lane]);
        float v2 = bf2f(h[(size_t)s2 * 64 + lane]);
        float v3 = bf2f(h[(size_t)s3 * 64 + lane]);
        float v4 = bf2f(h[(size_t)s4 * 64 + lane]);
        float v5 = bf2f(h[(size_t)s5 * 64 + lane]);
        float v6 = bf2f(h[(size_t)s6 * 64 + lane]);
        float v7 = bf2f(h[(size_t)s7 * 64 + lane]);
        float n0 = dinv[s0], n1 = dinv[s1], n2 = dinv[s2], n3 = dinv[s3];
        float n4 = dinv[s4], n5 = dinv[s5], n6 = dinv[s6], n7 = dinv[s7];
        acc  += v0 * (n0 * dvd);
        acc2 += v1 * (n1 * dvd);
        acc  += v2 * (n2 * dvd);
        acc2 += v3 * (n3 * dvd);
        acc  += v4 * (n4 * dvd);
        acc2 += v5 * (n5 * dvd);
        acc  += v6 * (n6 * dvd);
        acc2 += v7 * (n7 * dvd);
    }
    for (; j < deg; ++j) {
        int s0 = elist[base + j];
        acc += bf2f(h[(size_t)s0 * 64 + lane]) * (dinv[s0] * dvd);
    }
    accc[(size_t)wid * 64 + lane] = acc + acc2;
}

// ---------------- final gather: out[b] = accc[inv[x[b]]] -------------------
__global__ void k_gather(const int* __restrict__ x,
                         const int* __restrict__ inv,
                         const float* __restrict__ accc,
                         float* __restrict__ out) {
    int g = blockIdx.x * blockDim.x + threadIdx.x;   // [0, NX*64)
    if (g >= NX * 64) return;
    int v = x[g >> 6];
    out[g] = accc[(size_t)inv[v] * 64 + (g & 63)];
}

extern "C" void kernel_launch(void* const* d_in, const int* in_sizes, int n_in,
                              void* d_out, int out_size, void* d_ws, size_t ws_size,
                              hipStream_t stream) {
    const float* features = (const float*)d_in[0];
    const int*   edge     = (const int*)d_in[1];
    const float* W        = (const float*)d_in[2];
    const float* bias     = (const float*)d_in[3];
    const int*   x        = (const int*)d_in[4];
    float* out = (float*)d_out;

    char* ws = (char*)d_ws;
    unsigned short* h16      = (unsigned short*)(ws);            // 12,800,000 B
    unsigned int*   partial32= (unsigned int*)(ws + 12800000);   // 12,800,000 B
    int*            elist    = (int*)(ws + 12800000);            // overlay: live after k_reduce
    float*          accc     = (float*)(ws + 25600000);          //  4,194,304 B
    int*            cnt      = (int*)  (ws + 29794304);          //    400,000 B
    float*          dinv     = (float*)(ws + 30194304);          //    400,000 B
    int*            off      = (int*)  (ws + 30594304);          //    400,000 B
    int*            inv      = (int*)  (ws + 30994304);          //    400,000 B
    int*            nlist    = (int*)  (ws + 31394304);          //     65,536 B
    int*            cur      = (int*)  (ws + 31459840);          //    400,000 B
    unsigned long long* counters = (unsigned long long*)(ws + 31859840); // 32 B
    unsigned int*   bits     = (unsigned int*) (ws + 31859872);  //     12,512 B
    unsigned short* Wt       = (unsigned short*)(ws + 31872384); //     16,384 B
    // zero range: counters + bits = 31859840 .. 31872384 = 12,544 B = 784 float4

    const int* esrc = edge;
    const int* edst = edge + N_EDGES;

    k_zero    <<<4, 256, 0, stream>>>((float4*)(ws + 31859840));
    k_init    <<<65, 256, 0, stream>>>(x, bits, W, Wt);
    k_hist    <<<NRANGE * NSLICE, 256, 0, stream>>>(edst, partial32);
    k_reduce  <<<(N_NODES + 255) / 256, 256, 0, stream>>>(partial32, bits, cnt, dinv,
                                                          nlist, inv, off, cur, counters);
    k_fillgemm<<<FILLB + GEMMB, 256, 0, stream>>>(esrc, edst, bits, cur, elist,
                                                  features, Wt, h16);
    k_pull    <<<(NX * 64 + 255) / 256, 256, 0, stream>>>(nlist, (const int*)counters,
                                                          cnt, off, elist, h16, dinv,
                                                          bias, accc);
    k_gather  <<<(NX * 64 + 255) / 256, 256, 0, stream>>>(x, inv, accc, out);
}

// Round 11
// 121.274 us; speedup vs baseline: 17.3430x; 1.0091x over previous
//
#include <hip/hip_runtime.h>

#define N_NODES   100000
#define FIELD_DIM 128
#define EMBED_DIM 64
#define N_EDGES   3200000
#define NX        16384   // BATCH * NUM_FIELDS

#define NRANGE    4
#define RN        25000   // nodes per histogram range
#define RNH       12500   // packed u32 bins per range
#define NSLICE    64      // edge slices
#define SLICE_E   (N_EDGES / NSLICE)   // 50000 (< 65536: u16-safe per slice)
#define HISTB     (NRANGE * NSLICE)    // 256 hist blocks
#define GEMMB     ((N_NODES + 63) / 64) // 1563 gemm blocks
#define FILLB     (N_EDGES / 4 / 256)  // 3125 fill blocks (exact)

typedef short  bf16x8 __attribute__((ext_vector_type(8)));
typedef float  f32x4  __attribute__((ext_vector_type(4)));

__device__ __forceinline__ unsigned short f2bf(float x) {
    unsigned u = __float_as_uint(x);
    u += 0x7FFF + ((u >> 16) & 1);          // round-to-nearest-even
    return (unsigned short)(u >> 16);
}
__device__ __forceinline__ float bf2f(unsigned short b) {
    return __uint_as_float(((unsigned)b) << 16);
}
__device__ __forceinline__ unsigned pk2(float lo, float hi) {
    return (unsigned)f2bf(lo) | ((unsigned)f2bf(hi) << 16);
}

// ---------------- zero counters + bitmap (12544 B = 784 float4) ------------
__global__ void k_zero(float4* __restrict__ z4) {
    int i = blockIdx.x * blockDim.x + threadIdx.x;
    if (i < 784) z4[i] = make_float4(0.f, 0.f, 0.f, 0.f);
}

// ---------------- init: bitmap of needed nodes (blocks 0..63) + W^T --------
__global__ void k_init(const int* __restrict__ x, unsigned int* __restrict__ bits,
                       const float* __restrict__ W, unsigned short* __restrict__ Wt) {
    int b = blockIdx.x;
    if (b < 64) {
        int i = b * 256 + threadIdx.x;      // NX = 64*256 exactly
        int v = x[i];
        atomicOr(&bits[v >> 5], 1u << (v & 31));
    } else {
        for (int i = threadIdx.x; i < FIELD_DIM * EMBED_DIM; i += 256) {
            int k = i >> 6, c = i & 63;
            Wt[c * FIELD_DIM + k] = f2bf(W[i]);
        }
    }
}

// ---------------- fused hist + gemm (interleaved block roles) --------------
// Every 7th block (first 256 of them) is a hist block; the rest are gemm.
// Both roles co-resident on each CU: hist is BW/LDS-atomic-bound, gemm is
// MFMA/BW-bound -> true overlap instead of serial concatenation.
__global__ __launch_bounds__(256) void k_histgemm(const int* __restrict__ dst,
                                                  unsigned int* __restrict__ partial32,
                                                  const float* __restrict__ F,
                                                  const unsigned short* __restrict__ Wt,
                                                  unsigned short* __restrict__ h) {
    __shared__ unsigned int hist[RNH];        // 50,000 B (2 bins per u32)
    int b = blockIdx.x;
    int tid = threadIdx.x;
    bool ish = ((b % 7) == 0) && (b / 7 < HISTB);
    if (ish) {
        int hid = b / 7;
        int q = hid & 3, s = hid >> 2;
        for (int i = tid; i < RNH; i += 256) hist[i] = 0;
        __syncthreads();
        int lo = q * RN;
        const int4* dp = (const int4*)(dst + s * SLICE_E);
        for (int i = tid; i < SLICE_E / 4; i += 256) {
            int4 d = dp[i];
            int a;
            a = d.x - lo; if ((unsigned)a < RN) atomicAdd(&hist[a >> 1], 1u << ((a & 1) << 4));
            a = d.y - lo; if ((unsigned)a < RN) atomicAdd(&hist[a >> 1], 1u << ((a & 1) << 4));
            a = d.z - lo; if ((unsigned)a < RN) atomicAdd(&hist[a >> 1], 1u << ((a & 1) << 4));
            a = d.w - lo; if ((unsigned)a < RN) atomicAdd(&hist[a >> 1], 1u << ((a & 1) << 4));
        }
        __syncthreads();
        unsigned int* po = partial32 + (size_t)hid * RNH;
        for (int i = tid; i < RNH; i += 256) po[i] = hist[i];
        return;
    }
    // ---- gemm role: h(bf16) = F @ W, MFMA 16x16x32, B held in registers
    int gb = b - min((b + 6) / 7, HISTB);          // # hist blocks before b
    int wave = tid >> 6, lane = tid & 63;
    int l15 = lane & 15, kg = lane >> 4;

    const char* wb = (const char*)Wt;
    bf16x8 bfrag[4][4];
#pragma unroll
    for (int cb = 0; cb < 4; ++cb)
#pragma unroll
        for (int ks = 0; ks < 4; ++ks)
            bfrag[cb][ks] = *(const bf16x8*)(wb + (cb * 16 + l15) * 256 + ks * 64 + kg * 16);

    int row = gb * 64 + wave * 16 + l15;
    int rowc = min(row, N_NODES - 1);              // clamp; stores are guarded
    const float4* F4 = (const float4*)(F + (size_t)rowc * FIELD_DIM + kg * 8);

    f32x4 acc[4];
#pragma unroll
    for (int cb = 0; cb < 4; ++cb) acc[cb] = (f32x4){0.f, 0.f, 0.f, 0.f};

#pragma unroll
    for (int ks = 0; ks < 4; ++ks) {               // K = 32 per step
        float4 fa = F4[ks * 8];                    // k = 32ks + 8kg + 0..3
        float4 fb = F4[ks * 8 + 1];                // k = 32ks + 8kg + 4..7
        union { bf16x8 v; unsigned u[4]; } af;
        af.u[0] = pk2(fa.x, fa.y);
        af.u[1] = pk2(fa.z, fa.w);
        af.u[2] = pk2(fb.x, fb.y);
        af.u[3] = pk2(fb.z, fb.w);
#pragma unroll
        for (int cb = 0; cb < 4; ++cb)
            acc[cb] = __builtin_amdgcn_mfma_f32_16x16x32_bf16(af.v, bfrag[cb][ks],
                                                              acc[cb], 0, 0, 0);
    }
    int rbase = gb * 64 + wave * 16 + kg * 4;
#pragma unroll
    for (int r = 0; r < 4; ++r) {
        int orow = rbase + r;
        if (orow < N_NODES) {
            unsigned short* hp = h + (size_t)orow * 64 + l15;
#pragma unroll
            for (int cb = 0; cb < 4; ++cb) hp[cb * 16] = f2bf(acc[cb][r]);
        }
    }
}

// ---------------- reduce partials + dinv + compaction (1 atomic/block) -----
// 256 thr/block, thread = node. 64 slice loads in 4 register batches of 16.
__global__ __launch_bounds__(256) void k_reduce(const unsigned int* __restrict__ partial32,
                                                const unsigned int* __restrict__ bits,
                                                int* __restrict__ cnt,
                                                float* __restrict__ dinv,
                                                int* __restrict__ nlist,
                                                int* __restrict__ inv,
                                                int* __restrict__ off,
                                                int* __restrict__ cur16,
                                                unsigned long long* __restrict__ counters) {
    __shared__ int wtot[4], wedge[4], ptot[4], pedge[4];
    __shared__ unsigned int baseN, baseE;
    int tid = threadIdx.x;
    int v = blockIdx.x * 256 + tid;
    bool inb = (v < N_NODES);
    int vc = inb ? v : (N_NODES - 1);
    int q = vc / RN, loc = vc - q * RN;
    int i2 = loc >> 1, sh = (loc & 1) << 4;
    const unsigned int* p = partial32 + (size_t)q * RNH + i2;
    int c = 0;
#pragma unroll
    for (int sb = 0; sb < 4; ++sb) {
        unsigned int vals[16];
#pragma unroll
        for (int s = 0; s < 16; ++s) vals[s] = p[(size_t)(sb * 16 + s) * (NRANGE * RNH)];
#pragma unroll
        for (int s = 0; s < 16; ++s) c += (int)((vals[s] >> sh) & 0xFFFFu);
    }
    if (inb) {
        cnt[v] = c;
        dinv[v] = rsqrtf((float)c + 1.0f);    // +1 self loop
    }
    bool fl = inb && ((bits[v >> 5] >> (v & 31)) & 1u);
    int lane = tid & 63;
    int w = tid >> 6;
    unsigned long long mask = __ballot(fl);
    int cc = fl ? c : 0;
    int incl = cc;
#pragma unroll
    for (int o = 1; o < 64; o <<= 1) {
        int t = __shfl_up(incl, o);
        if (lane >= o) incl += t;
    }
    if (lane == 63) { wtot[w] = __popcll(mask); wedge[w] = incl; }
    int myi = __popcll(mask & ((1ull << lane) - 1));
    int excl = incl - cc;
    __syncthreads();
    if (tid == 0) {
        int t0 = wtot[0], t1 = wtot[1], t2 = wtot[2], t3 = wtot[3];
        int e0 = wedge[0], e1 = wedge[1], e2 = wedge[2], e3 = wedge[3];
        ptot[0] = 0; ptot[1] = t0; ptot[2] = t0 + t1; ptot[3] = t0 + t1 + t2;
        pedge[0] = 0; pedge[1] = e0; pedge[2] = e0 + e1; pedge[3] = e0 + e1 + e2;
        int bt = t0 + t1 + t2 + t3;
        int be = e0 + e1 + e2 + e3;
        if (bt > 0) {
            unsigned long long add = ((unsigned long long)(unsigned)be << 32) |
                                     (unsigned long long)(unsigned)bt;
            unsigned long long old = atomicAdd(counters, add);
            baseN = (unsigned)(old & 0xFFFFFFFFull);
            baseE = (unsigned)(old >> 32);
        } else {
            baseN = 0; baseE = 0;
        }
    }
    __syncthreads();
    if (fl) {
        int i = (int)baseN + ptot[w] + myi;
        int o = (int)baseE + pedge[w] + excl;
        nlist[i] = v;
        inv[v] = i;
        off[v] = o;
        cur16[v << 4] = o;        // one counter per 64B line: no line ping-pong
    }
}

// ---------------- fill in-edge lists: bitmap check + padded-cur atomic -----
__global__ __launch_bounds__(256) void k_fill(const int* __restrict__ src,
                                              const int* __restrict__ dst,
                                              const unsigned int* __restrict__ bits,
                                              int* __restrict__ cur16,
                                              int* __restrict__ elist) {
    int i = blockIdx.x * 256 + threadIdx.x;       // FILLB*256*4 = N_EDGES exactly
    int4 d4 = ((const int4*)dst)[i];
    int4 s4 = ((const int4*)src)[i];
#define FILL1(dd, ss) if ((bits[(unsigned)(dd) >> 5] >> ((dd) & 31)) & 1u) \
    { int p = atomicAdd(&cur16[(dd) << 4], 1); elist[p] = ss; }
    FILL1(d4.x, s4.x)
    FILL1(d4.y, s4.y)
    FILL1(d4.z, s4.z)
    FILL1(d4.w, s4.w)
#undef FILL1
}

// ---------------- pull: one wave per flagged node, 8-deep gather pipe ------
__global__ __launch_bounds__(256) void k_pull(const int* __restrict__ nlist,
                                              const int* __restrict__ counters,
                                              const int* __restrict__ cnt,
                                              const int* __restrict__ off,
                                              const int* __restrict__ elist,
                                              const unsigned short* __restrict__ h,
                                              const float* __restrict__ dinv,
                                              const float* __restrict__ bias,
                                              float* __restrict__ accc) {
    int t = blockIdx.x * blockDim.x + threadIdx.x;
    int wid = t >> 6;              // wave id = compact node index
    int lane = t & 63;
    if (wid >= counters[0]) return;   // low 32 bits of packed u64 = node count
    int v = nlist[wid];
    float dvd = dinv[v];
    int deg = cnt[v];
    int base = off[v];
    float acc = bf2f(h[(size_t)v * 64 + lane]) * (dvd * dvd) + bias[lane];
    float acc2 = 0.f;
    int j = 0;
    for (; j + 7 < deg; j += 8) {
        int s0 = elist[base + j + 0];
        int s1 = elist[base + j + 1];
        int s2 = elist[base + j + 2];
        int s3 = elist[base + j + 3];
        int s4 = elist[base + j + 4];
        int s5 = elist[base + j + 5];
        int s6 = elist[base + j + 6];
        int s7 = elist[base + j + 7];
        float v0 = bf2f(h[(size_t)s0 * 64 + lane]);
        float v1 = bf2f(h[(size_t)s1 * 64 + lane]);
        float v2 = bf2f(h[(size_t)s2 * 64 + lane]);
        float v3 = bf2f(h[(size_t)s3 * 64 + lane]);
        float v4 = bf2f(h[(size_t)s4 * 64 + lane]);
        float v5 = bf2f(h[(size_t)s5 * 64 + lane]);
        float v6 = bf2f(h[(size_t)s6 * 64 + lane]);
        float v7 = bf2f(h[(size_t)s7 * 64 + lane]);
        float n0 = dinv[s0], n1 = dinv[s1], n2 = dinv[s2], n3 = dinv[s3];
        float n4 = dinv[s4], n5 = dinv[s5], n6 = dinv[s6], n7 = dinv[s7];
        acc  += v0 * (n0 * dvd);
        acc2 += v1 * (n1 * dvd);
        acc  += v2 * (n2 * dvd);
        acc2 += v3 * (n3 * dvd);
        acc  += v4 * (n4 * dvd);
        acc2 += v5 * (n5 * dvd);
        acc  += v6 * (n6 * dvd);
        acc2 += v7 * (n7 * dvd);
    }
    for (; j < deg; ++j) {
        int s0 = elist[base + j];
        acc += bf2f(h[(size_t)s0 * 64 + lane]) * (dinv[s0] * dvd);
    }
    accc[(size_t)wid * 64 + lane] = acc + acc2;
}

// ---------------- final gather: out[b] = accc[inv[x[b]]] -------------------
__global__ void k_gather(const int* __restrict__ x,
                         const int* __restrict__ inv,
                         const float* __restrict__ accc,
                         float* __restrict__ out) {
    int g = blockIdx.x * blockDim.x + threadIdx.x;   // [0, NX*64)
    if (g >= NX * 64) return;
    int v = x[g >> 6];
    out[g] = accc[(size_t)inv[v] * 64 + (g & 63)];
}

extern "C" void kernel_launch(void* const* d_in, const int* in_sizes, int n_in,
                              void* d_out, int out_size, void* d_ws, size_t ws_size,
                              hipStream_t stream) {
    const float* features = (const float*)d_in[0];
    const int*   edge     = (const int*)d_in[1];
    const float* W        = (const float*)d_in[2];
    const float* bias     = (const float*)d_in[3];
    const int*   x        = (const int*)d_in[4];
    float* out = (float*)d_out;

    char* ws = (char*)d_ws;
    unsigned short* h16      = (unsigned short*)(ws);            // 12,800,000 B
    unsigned int*   partial32= (unsigned int*)(ws + 12800000);   // 12,800,000 B
    int*            elist    = (int*)(ws + 12800000);            // overlay: live after k_reduce
    float*          accc     = (float*)(ws + 25600000);          //  4,194,304 B
    int*            cnt      = (int*)  (ws + 29794304);          //    400,000 B
    float*          dinv     = (float*)(ws + 30194304);          //    400,000 B
    int*            off      = (int*)  (ws + 30594304);          //    400,000 B
    int*            inv      = (int*)  (ws + 30994304);          //    400,000 B
    int*            nlist    = (int*)  (ws + 31394304);          //     65,536 B
    unsigned long long* counters = (unsigned long long*)(ws + 31459840); // 32 B
    unsigned int*   bits     = (unsigned int*) (ws + 31459872);  //     12,512 B
    unsigned short* Wt       = (unsigned short*)(ws + 31472384); //     16,384 B
    int*            cur16    = (int*)  (ws + 31488768);          //  6,400,000 B (stride-16)
    // zero range: counters + bits = 31459840 .. 31472384 = 12,544 B = 784 float4

    const int* esrc = edge;
    const int* edst = edge + N_EDGES;

    k_zero    <<<4, 256, 0, stream>>>((float4*)(ws + 31459840));
    k_init    <<<65, 256, 0, stream>>>(x, bits, W, Wt);
    k_histgemm<<<HISTB + GEMMB, 256, 0, stream>>>(edst, partial32, features, Wt, h16);
    k_reduce  <<<(N_NODES + 255) / 256, 256, 0, stream>>>(partial32, bits, cnt, dinv,
                                                          nlist, inv, off, cur16, counters);
    k_fill    <<<FILLB, 256, 0, stream>>>(esrc, edst, bits, cur16, elist);
    k_pull    <<<(NX * 64 + 255) / 256, 256, 0, stream>>>(nlist, (const int*)counters,
                                                          cnt, off, elist, h16, dinv,
                                                          bias, accc);
    k_gather  <<<(NX * 64 + 255) / 256, 256, 0, stream>>>(x, inv, accc, out);
}

// Round 12
// 104.654 us; speedup vs baseline: 20.0972x; 1.1588x over previous
//
#include <hip/hip_runtime.h>

#define N_NODES   100000
#define FIELD_DIM 128
#define EMBED_DIM 64
#define N_EDGES   3200000
#define NX        16384   // BATCH * NUM_FIELDS

#define NRANGE    4
#define RN        25000   // nodes per histogram range
#define RNH       12500   // packed u32 bins per range
#define NSLICE    125     // edge slices
#define SLICE_E   (N_EDGES / NSLICE)   // 25600 (< 65536: u16-safe per slice)
#define HISTB     (NRANGE * NSLICE)    // 500 hist blocks
#define GEMMB     ((N_NODES + 63) / 64) // 1563 gemm blocks
#define FILLB     (N_EDGES / 4 / 256)  // 3125 fill blocks (exact)

typedef short  bf16x8 __attribute__((ext_vector_type(8)));
typedef float  f32x4  __attribute__((ext_vector_type(4)));

__device__ __forceinline__ unsigned short f2bf(float x) {
    unsigned u = __float_as_uint(x);
    u += 0x7FFF + ((u >> 16) & 1);          // round-to-nearest-even
    return (unsigned short)(u >> 16);
}
__device__ __forceinline__ float bf2f(unsigned short b) {
    return __uint_as_float(((unsigned)b) << 16);
}
__device__ __forceinline__ unsigned pk2(float lo, float hi) {
    return (unsigned)f2bf(lo) | ((unsigned)f2bf(hi) << 16);
}

// ---------------- zero counters + bitmap (12544 B = 784 float4) ------------
__global__ void k_zero(float4* __restrict__ z4) {
    int i = blockIdx.x * blockDim.x + threadIdx.x;
    if (i < 784) z4[i] = make_float4(0.f, 0.f, 0.f, 0.f);
}

// ---------------- init: bitmap of needed nodes (blocks 0..63) + W^T --------
__global__ void k_init(const int* __restrict__ x, unsigned int* __restrict__ bits,
                       const float* __restrict__ W, unsigned short* __restrict__ Wt) {
    int b = blockIdx.x;
    if (b < 64) {
        int i = b * 256 + threadIdx.x;      // NX = 64*256 exactly
        int v = x[i];
        atomicOr(&bits[v >> 5], 1u << (v & 31));
    } else {
        for (int i = threadIdx.x; i < FIELD_DIM * EMBED_DIM; i += 256) {
            int k = i >> 6, c = i & 63;
            Wt[c * FIELD_DIM + k] = f2bf(W[i]);
        }
    }
}

// ---------------- degree histogram: packed-u16 LDS, 4 ranges x 125 slices --
// 500 blocks (2/CU). 6400 int4 per slice = 256 thr x 25; 5 batches of 5
// register-staged loads to keep >=5 loads in flight per thread.
__global__ __launch_bounds__(256) void k_hist(const int* __restrict__ dst,
                                              unsigned int* __restrict__ partial32) {
    __shared__ unsigned int hist[RNH];        // 50,000 B (2 bins per u32)
    int tid = threadIdx.x;
    int q = blockIdx.x & 3, s = blockIdx.x >> 2;
    for (int i = tid; i < RNH; i += 256) hist[i] = 0;
    __syncthreads();
    int lo = q * RN;
    const int4* dp = (const int4*)(dst + s * SLICE_E);
#pragma unroll
    for (int bt = 0; bt < 5; ++bt) {
        int4 d[5];
#pragma unroll
        for (int u = 0; u < 5; ++u) d[u] = dp[tid + 256 * (bt * 5 + u)];
#pragma unroll
        for (int u = 0; u < 5; ++u) {
            int a;
            a = d[u].x - lo; if ((unsigned)a < RN) atomicAdd(&hist[a >> 1], 1u << ((a & 1) << 4));
            a = d[u].y - lo; if ((unsigned)a < RN) atomicAdd(&hist[a >> 1], 1u << ((a & 1) << 4));
            a = d[u].z - lo; if ((unsigned)a < RN) atomicAdd(&hist[a >> 1], 1u << ((a & 1) << 4));
            a = d[u].w - lo; if ((unsigned)a < RN) atomicAdd(&hist[a >> 1], 1u << ((a & 1) << 4));
        }
    }
    __syncthreads();
    unsigned int* po = partial32 + (size_t)blockIdx.x * RNH;
    for (int i = tid; i < RNH; i += 256) po[i] = hist[i];
}

// ---------------- reduce partials + dinv + compaction (1 atomic/block) -----
// 256 thr/block, thread = node. 125 slice loads in 5 register batches of 25.
__global__ __launch_bounds__(256) void k_reduce(const unsigned int* __restrict__ partial32,
                                                const unsigned int* __restrict__ bits,
                                                int* __restrict__ cnt,
                                                float* __restrict__ dinv,
                                                int* __restrict__ nlist,
                                                int* __restrict__ inv,
                                                int* __restrict__ off,
                                                int* __restrict__ cur16,
                                                unsigned long long* __restrict__ counters) {
    __shared__ int wtot[4], wedge[4], ptot[4], pedge[4];
    __shared__ unsigned int baseN, baseE;
    int tid = threadIdx.x;
    int v = blockIdx.x * 256 + tid;
    bool inb = (v < N_NODES);
    int vc = inb ? v : (N_NODES - 1);
    int q = vc / RN, loc = vc - q * RN;
    int i2 = loc >> 1, sh = (loc & 1) << 4;
    const unsigned int* p = partial32 + (size_t)q * RNH + i2;
    int c = 0;
#pragma unroll
    for (int sb = 0; sb < 5; ++sb) {
        unsigned int vals[25];
#pragma unroll
        for (int s = 0; s < 25; ++s) vals[s] = p[(size_t)(sb * 25 + s) * (NRANGE * RNH)];
#pragma unroll
        for (int s = 0; s < 25; ++s) c += (int)((vals[s] >> sh) & 0xFFFFu);
    }
    if (inb) {
        cnt[v] = c;
        dinv[v] = rsqrtf((float)c + 1.0f);    // +1 self loop
    }
    bool fl = inb && ((bits[v >> 5] >> (v & 31)) & 1u);
    int lane = tid & 63;
    int w = tid >> 6;
    unsigned long long mask = __ballot(fl);
    int cc = fl ? c : 0;
    int incl = cc;
#pragma unroll
    for (int o = 1; o < 64; o <<= 1) {
        int t = __shfl_up(incl, o);
        if (lane >= o) incl += t;
    }
    if (lane == 63) { wtot[w] = __popcll(mask); wedge[w] = incl; }
    int myi = __popcll(mask & ((1ull << lane) - 1));
    int excl = incl - cc;
    __syncthreads();
    if (tid == 0) {
        int t0 = wtot[0], t1 = wtot[1], t2 = wtot[2], t3 = wtot[3];
        int e0 = wedge[0], e1 = wedge[1], e2 = wedge[2], e3 = wedge[3];
        ptot[0] = 0; ptot[1] = t0; ptot[2] = t0 + t1; ptot[3] = t0 + t1 + t2;
        pedge[0] = 0; pedge[1] = e0; pedge[2] = e0 + e1; pedge[3] = e0 + e1 + e2;
        int bt = t0 + t1 + t2 + t3;
        int be = e0 + e1 + e2 + e3;
        if (bt > 0) {
            unsigned long long add = ((unsigned long long)(unsigned)be << 32) |
                                     (unsigned long long)(unsigned)bt;
            unsigned long long old = atomicAdd(counters, add);
            baseN = (unsigned)(old & 0xFFFFFFFFull);
            baseE = (unsigned)(old >> 32);
        } else {
            baseN = 0; baseE = 0;
        }
    }
    __syncthreads();
    if (fl) {
        int i = (int)baseN + ptot[w] + myi;
        int o = (int)baseE + pedge[w] + excl;
        nlist[i] = v;
        inv[v] = i;
        off[v] = o;
        cur16[v << 4] = o;        // one counter per 64B line
    }
}

// ---------------- fused fill + gemm (interleaved roles, both LDS-free) -----
// Every 3rd block is gemm (1563), rest fill (3125); co-resident on each CU so
// gemm's MFMA/BW work hides fill's atomic latency.
__global__ __launch_bounds__(256) void k_fillgemm(const int* __restrict__ src,
                                                  const int* __restrict__ dst,
                                                  const unsigned int* __restrict__ bits,
                                                  int* __restrict__ cur16,
                                                  int* __restrict__ elist,
                                                  const float* __restrict__ F,
                                                  const unsigned short* __restrict__ Wt,
                                                  unsigned short* __restrict__ h) {
    int b = blockIdx.x;
    int tid = threadIdx.x;
    bool isg = ((b % 3) == 0) && (b / 3 < GEMMB);
    if (!isg) {
        // ---- fill role: bitmap check + padded-cur atomic
        int fb = b - min(b / 3 + 1, GEMMB);
        int i = fb * 256 + tid;                   // FILLB*256*4 = N_EDGES exactly
        int4 d4 = ((const int4*)dst)[i];
        int4 s4 = ((const int4*)src)[i];
#define FILL1(dd, ss) if ((bits[(unsigned)(dd) >> 5] >> ((dd) & 31)) & 1u) \
        { int p = atomicAdd(&cur16[(dd) << 4], 1); elist[p] = ss; }
        FILL1(d4.x, s4.x)
        FILL1(d4.y, s4.y)
        FILL1(d4.z, s4.z)
        FILL1(d4.w, s4.w)
#undef FILL1
        return;
    }
    // ---- gemm role: h(bf16) = F @ W, MFMA 16x16x32, B held in registers
    int gb = b / 3;
    int wave = tid >> 6, lane = tid & 63;
    int l15 = lane & 15, kg = lane >> 4;

    const char* wb = (const char*)Wt;
    bf16x8 bfrag[4][4];
#pragma unroll
    for (int cb = 0; cb < 4; ++cb)
#pragma unroll
        for (int ks = 0; ks < 4; ++ks)
            bfrag[cb][ks] = *(const bf16x8*)(wb + (cb * 16 + l15) * 256 + ks * 64 + kg * 16);

    int row = gb * 64 + wave * 16 + l15;
    int rowc = min(row, N_NODES - 1);              // clamp; stores are guarded
    const float4* F4 = (const float4*)(F + (size_t)rowc * FIELD_DIM + kg * 8);

    f32x4 acc[4];
#pragma unroll
    for (int cb = 0; cb < 4; ++cb) acc[cb] = (f32x4){0.f, 0.f, 0.f, 0.f};

#pragma unroll
    for (int ks = 0; ks < 4; ++ks) {               // K = 32 per step
        float4 fa = F4[ks * 8];                    // k = 32ks + 8kg + 0..3
        float4 fb = F4[ks * 8 + 1];                // k = 32ks + 8kg + 4..7
        union { bf16x8 v; unsigned u[4]; } af;
        af.u[0] = pk2(fa.x, fa.y);
        af.u[1] = pk2(fa.z, fa.w);
        af.u[2] = pk2(fb.x, fb.y);
        af.u[3] = pk2(fb.z, fb.w);
#pragma unroll
        for (int cb = 0; cb < 4; ++cb)
            acc[cb] = __builtin_amdgcn_mfma_f32_16x16x32_bf16(af.v, bfrag[cb][ks],
                                                              acc[cb], 0, 0, 0);
    }
    int rbase = gb * 64 + wave * 16 + kg * 4;
#pragma unroll
    for (int r = 0; r < 4; ++r) {
        int orow = rbase + r;
        if (orow < N_NODES) {
            unsigned short* hp = h + (size_t)orow * 64 + l15;
#pragma unroll
            for (int cb = 0; cb < 4; ++cb) hp[cb * 16] = f2bf(acc[cb][r]);
        }
    }
}

// ---------------- pull: one wave per flagged node, 8-deep gather pipe ------
__global__ __launch_bounds__(256) void k_pull(const int* __restrict__ nlist,
                                              const int* __restrict__ counters,
                                              const int* __restrict__ cnt,
                                              const int* __restrict__ off,
                                              const int* __restrict__ elist,
                                              const unsigned short* __restrict__ h,
                                              const float* __restrict__ dinv,
                                              const float* __restrict__ bias,
                                              float* __restrict__ accc) {
    int t = blockIdx.x * blockDim.x + threadIdx.x;
    int wid = t >> 6;              // wave id = compact node index
    int lane = t & 63;
    if (wid >= counters[0]) return;   // low 32 bits of packed u64 = node count
    int v = nlist[wid];
    float dvd = dinv[v];
    int deg = cnt[v];
    int base = off[v];
    float acc = bf2f(h[(size_t)v * 64 + lane]) * (dvd * dvd) + bias[lane];
    float acc2 = 0.f;
    int j = 0;
    for (; j + 7 < deg; j += 8) {
        int s0 = elist[base + j + 0];
        int s1 = elist[base + j + 1];
        int s2 = elist[base + j + 2];
        int s3 = elist[base + j + 3];
        int s4 = elist[base + j + 4];
        int s5 = elist[base + j + 5];
        int s6 = elist[base + j + 6];
        int s7 = elist[base + j + 7];
        float v0 = bf2f(h[(size_t)s0 * 64 + lane]);
        float v1 = bf2f(h[(size_t)s1 * 64 + lane]);
        float v2 = bf2f(h[(size_t)s2 * 64 + lane]);
        float v3 = bf2f(h[(size_t)s3 * 64 + lane]);
        float v4 = bf2f(h[(size_t)s4 * 64 + lane]);
        float v5 = bf2f(h[(size_t)s5 * 64 + lane]);
        float v6 = bf2f(h[(size_t)s6 * 64 + lane]);
        float v7 = bf2f(h[(size_t)s7 * 64 + lane]);
        float n0 = dinv[s0], n1 = dinv[s1], n2 = dinv[s2], n3 = dinv[s3];
        float n4 = dinv[s4], n5 = dinv[s5], n6 = dinv[s6], n7 = dinv[s7];
        acc  += v0 * (n0 * dvd);
        acc2 += v1 * (n1 * dvd);
        acc  += v2 * (n2 * dvd);
        acc2 += v3 * (n3 * dvd);
        acc  += v4 * (n4 * dvd);
        acc2 += v5 * (n5 * dvd);
        acc  += v6 * (n6 * dvd);
        acc2 += v7 * (n7 * dvd);
    }
    for (; j < deg; ++j) {
        int s0 = elist[base + j];
        acc += bf2f(h[(size_t)s0 * 64 + lane]) * (dinv[s0] * dvd);
    }
    accc[(size_t)wid * 64 + lane] = acc + acc2;
}

// ---------------- final gather: out[b] = accc[inv[x[b]]] -------------------
__global__ void k_gather(const int* __restrict__ x,
                         const int* __restrict__ inv,
                         const float* __restrict__ accc,
                         float* __restrict__ out) {
    int g = blockIdx.x * blockDim.x + threadIdx.x;   // [0, NX*64)
    if (g >= NX * 64) return;
    int v = x[g >> 6];
    out[g] = accc[(size_t)inv[v] * 64 + (g & 63)];
}

extern "C" void kernel_launch(void* const* d_in, const int* in_sizes, int n_in,
                              void* d_out, int out_size, void* d_ws, size_t ws_size,
                              hipStream_t stream) {
    const float* features = (const float*)d_in[0];
    const int*   edge     = (const int*)d_in[1];
    const float* W        = (const float*)d_in[2];
    const float* bias     = (const float*)d_in[3];
    const int*   x        = (const int*)d_in[4];
    float* out = (float*)d_out;

    char* ws = (char*)d_ws;
    unsigned short* h16      = (unsigned short*)(ws);            // 12,800,000 B
    unsigned int*   partial32= (unsigned int*)(ws + 12800000);   // 25,000,000 B
    int*            elist    = (int*)(ws + 12800000);            // overlay: live after k_reduce
    float*          accc     = (float*)(ws + 37800000);          //  4,194,304 B
    int*            cnt      = (int*)  (ws + 41994304);          //    400,000 B
    float*          dinv     = (float*)(ws + 42394304);          //    400,000 B
    int*            off      = (int*)  (ws + 42794304);          //    400,000 B
    int*            inv      = (int*)  (ws + 43194304);          //    400,000 B
    int*            nlist    = (int*)  (ws + 43594304);          //     65,536 B
    unsigned long long* counters = (unsigned long long*)(ws + 43659840); // 32 B
    unsigned int*   bits     = (unsigned int*) (ws + 43659872);  //     12,512 B
    unsigned short* Wt       = (unsigned short*)(ws + 43672384); //     16,384 B
    int*            cur16    = (int*)  (ws + 43688768);          //  6,400,000 B (stride-16)
    // zero range: counters + bits = 43659840 .. 43672384 = 12,544 B = 784 float4

    const int* esrc = edge;
    const int* edst = edge + N_EDGES;

    k_zero    <<<4, 256, 0, stream>>>((float4*)(ws + 43659840));
    k_init    <<<65, 256, 0, stream>>>(x, bits, W, Wt);
    k_hist    <<<HISTB, 256, 0, stream>>>(edst, partial32);
    k_reduce  <<<(N_NODES + 255) / 256, 256, 0, stream>>>(partial32, bits, cnt, dinv,
                                                          nlist, inv, off, cur16, counters);
    k_fillgemm<<<FILLB + GEMMB, 256, 0, stream>>>(esrc, edst, bits, cur16, elist,
                                                  features, Wt, h16);
    k_pull    <<<(NX * 64 + 255) / 256, 256, 0, stream>>>(nlist, (const int*)counters,
                                                          cnt, off, elist, h16, dinv,
                                                          bias, accc);
    k_gather  <<<(NX * 64 + 255) / 256, 256, 0, stream>>>(x, inv, accc, out);
}